// Round 8
// baseline (122.295 us; speedup 1.0000x reference)
//
#include <hip/hip_runtime.h>
#include <hip/hip_bf16.h>
#include <math.h>

typedef __attribute__((ext_vector_type(8))) short short8;
typedef __attribute__((ext_vector_type(4))) float f32x4;

#define T_TOK 2048
#define D_DIM 512
#define F_DIM 2048
#define E_NUM 8
#define MAXT2 23   // >= sum_e ceil(cnt_e/128) <= 16+7

__device__ __forceinline__ unsigned short f2bf(float f) {
  union { float f; unsigned u; } c; c.f = f;
  unsigned u = c.u;
  return (unsigned short)((u + 0x7fffu + ((u >> 16) & 1u)) >> 16);
}

__device__ __forceinline__ void gld16(const void* g, void* l) {
  __builtin_amdgcn_global_load_lds((const __attribute__((address_space(1))) int*)g,
                                   (__attribute__((address_space(3))) int*)l, 16, 0, 0);
}

// ---- routing: logits (32-way K-split) + top-2 + weight; also converts x->bf16 ----
__global__ __launch_bounds__(256) void k_route(const float* __restrict__ x,
                                               const float* __restrict__ Wg,
                                               int* __restrict__ jbuf,
                                               float* __restrict__ wbuf,
                                               unsigned short* __restrict__ xb) {
  int gid = blockIdx.x * 256 + threadIdx.x;
  int t = gid >> 5, seg = gid & 31;
  const float* xp = x + (size_t)t * D_DIM + seg * 16;
  unsigned short* xo = xb + (size_t)t * D_DIM + seg * 16;
  float acc[8];
#pragma unroll
  for (int e = 0; e < 8; ++e) acc[e] = 0.f;
#pragma unroll
  for (int i = 0; i < 4; ++i) {
    float4 v = *(const float4*)(xp + i * 4);
    ushort4 o;
    o.x = f2bf(v.x); o.y = f2bf(v.y); o.z = f2bf(v.z); o.w = f2bf(v.w);
    *(ushort4*)(xo + i * 4) = o;
    const float* xs = (const float*)&v;
#pragma unroll
    for (int q = 0; q < 4; ++q) {
      int d = seg * 16 + i * 4 + q;
      const float4* wr = (const float4*)(Wg + (size_t)d * 8);
      float4 w0 = wr[0], w1 = wr[1];
      acc[0] += xs[q] * w0.x; acc[1] += xs[q] * w0.y;
      acc[2] += xs[q] * w0.z; acc[3] += xs[q] * w0.w;
      acc[4] += xs[q] * w1.x; acc[5] += xs[q] * w1.y;
      acc[6] += xs[q] * w1.z; acc[7] += xs[q] * w1.w;
    }
  }
#pragma unroll
  for (int off = 1; off < 32; off <<= 1)
#pragma unroll
    for (int e = 0; e < 8; ++e) acc[e] += __shfl_xor(acc[e], off);
  if (seg == 0) {
    float l0 = -1e30f, l1 = -1e30f; int i0 = 0, i1 = 0;
#pragma unroll
    for (int e = 0; e < 8; ++e) {
      float l = acc[e];
      if (l > l0) { l1 = l0; i1 = i0; l0 = l; i0 = e; }
      else if (l > l1) { l1 = l; i1 = e; }
    }
    int j; float w;
    if (i0 > i1) { j = i0; w = 1.f / (1.f + expf(l1 - l0)); }
    else         { j = i1; w = 1.f / (1.f + expf(l0 - l1)); }
    jbuf[t] = j; wbuf[t] = w;
  }
}

// ---- bucket: counts, bases, compact token list, tile list for BM=128 (ffn2) ----
__global__ __launch_bounds__(256) void k_bucket(const int* __restrict__ jbuf,
                                                int* __restrict__ cntp,
                                                int* __restrict__ basep,
                                                int* __restrict__ list,
                                                int* __restrict__ tl2,
                                                int* __restrict__ ntl) {
  __shared__ int scnt[8], scur[8];
  int tid = threadIdx.x;
  if (tid < 8) scnt[tid] = 0;
  __syncthreads();
  for (int t = tid; t < T_TOK; t += 256) atomicAdd(&scnt[jbuf[t]], 1);
  __syncthreads();
  if (tid == 0) {
    int run = 0;
    for (int e = 0; e < 8; ++e) {
      cntp[e] = scnt[e]; basep[e] = run; scur[e] = run;
      run += scnt[e];
    }
    int n2 = 0, bb = 0;
    for (int e = 0; e < 8; ++e) {
      for (int m = 0; m < scnt[e]; m += 128) tl2[n2++] = (e << 16) | (bb + m);
      bb += scnt[e];
    }
    ntl[1] = n2;
  }
  __syncthreads();
  for (int t = tid; t < T_TOK; t += 256) {
    int j = jbuf[t];
    int p = atomicAdd(&scur[j], 1);
    list[p] = t;
  }
}

// ---- pass 1: block=(e, 32-col panel); B one-time in LDS (fragment order); BM=32 m-loop ----
__global__ __launch_bounds__(256, 2) void k_ffn1(const unsigned short* __restrict__ xb,
                                                 const float* __restrict__ W1,
                                                 const float* __restrict__ W3,
                                                 const int* __restrict__ cntp,
                                                 const int* __restrict__ basep,
                                                 const int* __restrict__ list,
                                                 unsigned short* __restrict__ hbuf) {
  int e = blockIdx.x & 7, np = blockIdx.x >> 3;   // np: 64 panels of 32 f-cols
  int cnt = cntp[e];
  if (cnt == 0) return;
  int base = basep[e], lim = base + cnt;
  int nm = (cnt + 31) >> 5;
  __shared__ unsigned short sA[32 * 512];            // 32 KB, XOR-swizzled 16B slots
  __shared__ unsigned short sB[2 * 2 * 16 * 512];    // 32 KB [mat][wcb][kf][64][8]
  int tid = threadIdx.x, wv = tid >> 6, l = tid & 63;
  int wr = wv >> 1, wc = wv & 1;

  // one-time B pull: coalesced f32 float4 reads -> cvt -> fragment-order LDS scatter
#pragma unroll
  for (int mat = 0; mat < 2; ++mat) {
    const float* wp = (mat ? W3 : W1) + (size_t)e * D_DIM * F_DIM + np * 32;
#pragma unroll
    for (int i = 0; i < 16; ++i) {
      int idx = i * 256 + tid;               // 0..4095 over [512 rows][8 float4]
      int row = idx >> 3, c4 = (idx & 7) * 4;
      float4 v = *(const float4*)(wp + (size_t)row * F_DIM + c4);
      int kf = row >> 5, lr = ((row >> 3) & 3) * 16, j = row & 7;
      const float* vs = (const float*)&v;
#pragma unroll
      for (int q = 0; q < 4; ++q) {
        int n = c4 + q;
        sB[mat * 16384 + (n >> 4) * 8192 + kf * 512 + (lr + (n & 15)) * 8 + j] = f2bf(vs[q]);
      }
    }
  }
  // first __syncthreads below (after stage of im=0) publishes sB before any read

  for (int im = 0; im < nm; ++im) {
    int g0 = base + im * 32;
    // stage A tile [32][512]: wave wv stages rows wv*8..+7, swizzled source slots
#pragma unroll
    for (int it = 0; it < 8; ++it) {
      int row = wv * 8 + it;
      int gr = g0 + row; if (gr >= lim) gr = lim - 1;
      int tok = list[gr];
      int slot = (l & 56) | ((l & 7) ^ (row & 7));
      gld16(xb + (size_t)tok * D_DIM + slot * 8, sA + row * 512);
    }
    __syncthreads();   // drain gld16 (and, on im=0, the sB writes)

    f32x4 au = (f32x4){0.f, 0.f, 0.f, 0.f};
    f32x4 av = (f32x4){0.f, 0.f, 0.f, 0.f};
#pragma unroll
    for (int kf = 0; kf < 16; ++kf) {
      int r = wr * 16 + (l & 15);
      int slot = kf * 4 + (l >> 4);
      int swz = (slot & 56) | ((slot & 7) ^ (r & 7));
      short8 a  = *(const short8*)(sA + r * 512 + swz * 8);
      short8 b1 = *(const short8*)(sB + wc * 8192 + kf * 512 + l * 8);
      short8 b3 = *(const short8*)(sB + 16384 + wc * 8192 + kf * 512 + l * 8);
      au = __builtin_amdgcn_mfma_f32_16x16x32_bf16(a, b1, au, 0, 0, 0);
      av = __builtin_amdgcn_mfma_f32_16x16x32_bf16(a, b3, av, 0, 0, 0);
    }
    __syncthreads();   // all sA reads done before next m-iter restages

    int cloc = l & 15, rb = (l >> 4) * 4;
    int col = np * 32 + wc * 16 + cloc;
#pragma unroll
    for (int r = 0; r < 4; ++r) {
      int gr = g0 + wr * 16 + rb + r;
      if (gr < lim) {
        float uu = au[r], vv = av[r];
        float hh = (uu / (1.f + expf(-uu))) * vv;
        hbuf[(size_t)gr * F_DIM + col] = f2bf(hh);
      }
    }
  }
}

// ---- pass 2: BM=128 BN=32 BK=128; A dbuf (gld16 swizzled) + B dbuf (coalesced->frag LDS) ----
__global__ __launch_bounds__(256, 2) void k_ffn2(const unsigned short* __restrict__ hbuf,
                                                 const float* __restrict__ W2,
                                                 const int* __restrict__ cntp,
                                                 const int* __restrict__ basep,
                                                 const int* __restrict__ list,
                                                 const int* __restrict__ tl2,
                                                 const int* __restrict__ ntl,
                                                 const float* __restrict__ wbuf,
                                                 float* __restrict__ out) {
  if ((int)blockIdx.x >= ntl[1]) return;
  int pk = tl2[blockIdx.x];
  int e = pk >> 16, g0 = pk & 0xffff;
  int lim = basep[e] + cntp[e];
  int nt = blockIdx.y;               // 16 panels of 32 d-cols
  __shared__ unsigned short sA[2 * 16384];   // 64 KB: [buf][128 rows][128 k], swizzled slots
  __shared__ unsigned short sB[2 * 4096];    // 16 KB: [buf][wcb][kf][64][8]
  int tid = threadIdx.x, wv = tid >> 6, l = tid & 63;
  int wr = wv >> 1, wc = wv & 1;
  const float* wp = W2 + (size_t)e * F_DIM * D_DIM + nt * 32;

  auto stageA = [&](int buf, int ck) {
#pragma unroll
    for (int it = 0; it < 8; ++it) {
      int row0 = wv * 32 + it * 4;             // wave-uniform
      int row = row0 + (l >> 4);
      int gr = g0 + row; if (gr > T_TOK - 1) gr = T_TOK - 1;
      int sl = (l & 8) | ((l & 7) ^ (row & 7));
      gld16(hbuf + (size_t)gr * F_DIM + ck * 128 + sl * 8, sA + buf * 16384 + row0 * 128);
    }
  };

  float4 vB[4];
  auto loadB = [&](int ck) {     // coalesced: [128 rows][8 float4] -> 4 float4/thread
#pragma unroll
    for (int i = 0; i < 4; ++i) {
      int idx = i * 256 + tid;
      int row = idx >> 3, c4 = (idx & 7) * 4;
      vB[i] = *(const float4*)(wp + (size_t)(ck * 128 + row) * D_DIM + c4);
    }
  };
  auto writeB = [&](int buf) {   // cvt + fragment-order scatter
#pragma unroll
    for (int i = 0; i < 4; ++i) {
      int idx = i * 256 + tid;
      int row = idx >> 3, c4 = (idx & 7) * 4;
      int kf = row >> 5, lr = ((row >> 3) & 3) * 16, j = row & 7;
      const float* vs = (const float*)&vB[i];
#pragma unroll
      for (int q = 0; q < 4; ++q) {
        int n = c4 + q;
        sB[buf * 4096 + (n >> 4) * 2048 + kf * 512 + (lr + (n & 15)) * 8 + j] = f2bf(vs[q]);
      }
    }
  };

  f32x4 acc[4];
#pragma unroll
  for (int i = 0; i < 4; ++i) acc[i] = (f32x4){0.f, 0.f, 0.f, 0.f};

  auto compute = [&](int buf) {
#pragma unroll
    for (int kf = 0; kf < 4; ++kf) {
      short8 b = *(const short8*)(sB + buf * 4096 + wc * 2048 + kf * 512 + l * 8);
#pragma unroll
      for (int i = 0; i < 4; ++i) {
        int r = wr * 64 + i * 16 + (l & 15);
        int slot = kf * 4 + (l >> 4);
        int swz = (slot & 8) | ((slot & 7) ^ (r & 7));
        short8 a = *(const short8*)(sA + buf * 16384 + r * 128 + swz * 8);
        acc[i] = __builtin_amdgcn_mfma_f32_16x16x32_bf16(a, b, acc[i], 0, 0, 0);
      }
    }
  };

  loadB(0);
  stageA(0, 0);
  writeB(0);
  __syncthreads();
  int cur = 0;
  for (int ck = 0; ck < 16; ++ck) {
    if (ck < 15) {               // T14 split: issue next-chunk loads before compute
      loadB(ck + 1);
      stageA(cur ^ 1, ck + 1);
    }
    compute(cur);
    if (ck < 15) writeB(cur ^ 1);   // lands after compute hid the load latency
    __syncthreads();
    cur ^= 1;
  }

  int cloc = l & 15, rb = (l >> 4) * 4;
#pragma unroll
  for (int i = 0; i < 4; ++i)
#pragma unroll
    for (int r = 0; r < 4; ++r) {
      int gr = g0 + wr * 64 + i * 16 + rb + r;
      if (gr < lim) {
        int tok = list[gr];
        out[(size_t)tok * D_DIM + nt * 32 + wc * 16 + cloc] = wbuf[tok] * acc[i][r];
      }
    }
}

// ---------------- launch ----------------
extern "C" void kernel_launch(void* const* d_in, const int* in_sizes, int n_in,
                              void* d_out, int out_size, void* d_ws, size_t ws_size,
                              hipStream_t stream) {
  const float* x  = (const float*)d_in[0];
  const float* Wg = (const float*)d_in[1];
  const float* W1 = (const float*)d_in[2];
  const float* W2 = (const float*)d_in[3];
  const float* W3 = (const float*)d_in[4];
  float* out = (float*)d_out;
  char* ws = (char*)d_ws;

  int*            jbuf  = (int*)(ws + 0);
  float*          wbuf  = (float*)(ws + 8192);
  int*            cntp  = (int*)(ws + 16384);
  int*            basep = (int*)(ws + 16448);
  int*            list  = (int*)(ws + 16640);      // int[2048]
  int*            tl2   = (int*)(ws + 25088);      // int[24]
  int*            ntl   = (int*)(ws + 25600);      // int[2]
  unsigned short* xb    = (unsigned short*)(ws + 32768);             // bf16 [2048][512]
  unsigned short* hbuf  = (unsigned short*)(ws + 32768 + 2097152);   // bf16 [2048][2048]

  k_route<<<dim3(256), dim3(256), 0, stream>>>(x, Wg, jbuf, wbuf, xb);
  k_bucket<<<dim3(1), dim3(256), 0, stream>>>(jbuf, cntp, basep, list, tl2, ntl);
  k_ffn1<<<dim3(512), dim3(256), 0, stream>>>(xb, W1, W3, cntp, basep, list, hbuf);
  k_ffn2<<<dim3(MAXT2, 16), dim3(256), 0, stream>>>(hbuf, W2, cntp, basep, list, tl2, ntl, wbuf, out);
}

// Round 9
// 106.930 us; speedup vs baseline: 1.1437x; 1.1437x over previous
//
#include <hip/hip_runtime.h>
#include <hip/hip_bf16.h>
#include <math.h>

typedef __attribute__((ext_vector_type(8))) short short8;
typedef __attribute__((ext_vector_type(4))) float f32x4;

#define T_TOK 2048
#define D_DIM 512
#define F_DIM 2048
#define E_NUM 8
#define MAXT1 40   // >= sum_e ceil(cnt_e/64) <= 32+7

__device__ __forceinline__ unsigned short f2bf(float f) {
  union { float f; unsigned u; } c; c.f = f;
  unsigned u = c.u;
  return (unsigned short)((u + 0x7fffu + ((u >> 16) & 1u)) >> 16);
}

__device__ __forceinline__ void gld16(const void* g, void* l) {
  __builtin_amdgcn_global_load_lds((const __attribute__((address_space(1))) int*)g,
                                   (__attribute__((address_space(3))) int*)l, 16, 0, 0);
}

// ---- routing: logits (32-way K-split) + top-2 + weight; also converts x->bf16 ----
__global__ __launch_bounds__(256) void k_route(const float* __restrict__ x,
                                               const float* __restrict__ Wg,
                                               int* __restrict__ jbuf,
                                               float* __restrict__ wbuf,
                                               unsigned short* __restrict__ xb) {
  int gid = blockIdx.x * 256 + threadIdx.x;
  int t = gid >> 5, seg = gid & 31;
  const float* xp = x + (size_t)t * D_DIM + seg * 16;
  unsigned short* xo = xb + (size_t)t * D_DIM + seg * 16;
  float acc[8];
#pragma unroll
  for (int e = 0; e < 8; ++e) acc[e] = 0.f;
#pragma unroll
  for (int i = 0; i < 4; ++i) {
    float4 v = *(const float4*)(xp + i * 4);
    ushort4 o;
    o.x = f2bf(v.x); o.y = f2bf(v.y); o.z = f2bf(v.z); o.w = f2bf(v.w);
    *(ushort4*)(xo + i * 4) = o;
    const float* xs = (const float*)&v;
#pragma unroll
    for (int q = 0; q < 4; ++q) {
      int d = seg * 16 + i * 4 + q;
      const float4* wr = (const float4*)(Wg + (size_t)d * 8);
      float4 w0 = wr[0], w1 = wr[1];
      acc[0] += xs[q] * w0.x; acc[1] += xs[q] * w0.y;
      acc[2] += xs[q] * w0.z; acc[3] += xs[q] * w0.w;
      acc[4] += xs[q] * w1.x; acc[5] += xs[q] * w1.y;
      acc[6] += xs[q] * w1.z; acc[7] += xs[q] * w1.w;
    }
  }
#pragma unroll
  for (int off = 1; off < 32; off <<= 1)
#pragma unroll
    for (int e = 0; e < 8; ++e) acc[e] += __shfl_xor(acc[e], off);
  if (seg == 0) {
    float l0 = -1e30f, l1 = -1e30f; int i0 = 0, i1 = 0;
#pragma unroll
    for (int e = 0; e < 8; ++e) {
      float l = acc[e];
      if (l > l0) { l1 = l0; i1 = i0; l0 = l; i0 = e; }
      else if (l > l1) { l1 = l; i1 = e; }
    }
    int j; float w;
    if (i0 > i1) { j = i0; w = 1.f / (1.f + expf(l1 - l0)); }
    else         { j = i1; w = 1.f / (1.f + expf(l0 - l1)); }
    jbuf[t] = j; wbuf[t] = w;
  }
}

// ---- bucket: counts, bases, compact token list, compact tile list (BM=64) ----
__global__ __launch_bounds__(256) void k_bucket(const int* __restrict__ jbuf,
                                                int* __restrict__ cntp,
                                                int* __restrict__ basep,
                                                int* __restrict__ list,
                                                int* __restrict__ tl1,
                                                int* __restrict__ ntl) {
  __shared__ int scnt[8], scur[8];
  int tid = threadIdx.x;
  if (tid < 8) scnt[tid] = 0;
  __syncthreads();
  for (int t = tid; t < T_TOK; t += 256) atomicAdd(&scnt[jbuf[t]], 1);
  __syncthreads();
  if (tid == 0) {
    int run = 0;
    for (int e = 0; e < 8; ++e) {
      cntp[e] = scnt[e]; basep[e] = run; scur[e] = run;
      run += scnt[e];
    }
    int n1 = 0, bb = 0;
    for (int e = 0; e < 8; ++e) {
      for (int m = 0; m < scnt[e]; m += 64) tl1[n1++] = (e << 16) | (bb + m);
      bb += scnt[e];
    }
    ntl[0] = n1;
  }
  __syncthreads();
  for (int t = tid; t < T_TOK; t += 256) {
    int j = jbuf[t];
    int p = atomicAdd(&scur[j], 1);
    list[p] = t;
  }
}

// ---- weight reformat: [Z][K][N] f32 -> fragment-major bf16 [Z][N/16][K/32][64][8] ----
__global__ __launch_bounds__(256) void k_wfrag(const float* __restrict__ inA,
                                               const float* __restrict__ inB,
                                               unsigned short* __restrict__ outA,
                                               unsigned short* __restrict__ outB,
                                               int K, int N) {
  __shared__ float tile[64][65];
  int z = blockIdx.z;
  const float* in; unsigned short* out;
  size_t zsz = (size_t)(K / 32) * (N / 16) * 512;
  if (z < 8) { in = inA + (size_t)z * K * N;       out = outA + (size_t)z * zsz; }
  else       { in = inB + (size_t)(z - 8) * K * N; out = outB + (size_t)(z - 8) * zsz; }
  int n0 = blockIdx.x * 64, k0 = blockIdx.y * 64;
  int tid = threadIdx.x;
  int lr = tid >> 4, lc = tid & 15;
#pragma unroll
  for (int it = 0; it < 4; ++it) {
    int row = it * 16 + lr;
    float4 v = *(const float4*)(in + (size_t)(k0 + row) * N + n0 + lc * 4);
    tile[row][lc * 4 + 0] = v.x;
    tile[row][lc * 4 + 1] = v.y;
    tile[row][lc * 4 + 2] = v.z;
    tile[row][lc * 4 + 3] = v.w;
  }
  __syncthreads();
  int wv = tid >> 6, l = tid & 63;
#pragma unroll
  for (int q = 0; q < 2; ++q) {
    int fid = wv * 2 + q;
    int nb = fid >> 1, kb = fid & 1;
    short8 o;
#pragma unroll
    for (int j = 0; j < 8; ++j)
      o[j] = (short)f2bf(tile[kb * 32 + (l >> 4) * 8 + j][nb * 16 + (l & 15)]);
    unsigned short* op = out + (((size_t)(n0 / 16 + nb) * (K / 32)) + (k0 / 32 + kb)) * 512 + l * 8;
    *(short8*)op = o;
  }
}

// ---- pass 1: A staged ONCE per block; barrier-free stream of B-frags over 4 panels ----
__global__ __launch_bounds__(256, 2) void k_ffn1(const unsigned short* __restrict__ xb,
                                                 const unsigned short* __restrict__ w1f,
                                                 const unsigned short* __restrict__ w3f,
                                                 const int* __restrict__ cntp,
                                                 const int* __restrict__ basep,
                                                 const int* __restrict__ list,
                                                 const int* __restrict__ tl1,
                                                 const int* __restrict__ ntl,
                                                 unsigned short* __restrict__ hbuf) {
  if ((int)blockIdx.x >= ntl[0]) return;
  int pk = tl1[blockIdx.x];
  int e = pk >> 16, g0 = pk & 0xffff;
  int lim = basep[e] + cntp[e];
  int npg = blockIdx.y;                  // 16 groups of 4 panels (np = npg*4+g)
  __shared__ unsigned short sA[64 * 512];   // 64 KB, XOR-swizzled 16B slots
  int tid = threadIdx.x, wv = tid >> 6, l = tid & 63;
  int wr = wv >> 1, wc = wv & 1;

  // one-time A stage: wave wv stages rows wv*16..+15 (1 row = 1 KB = one gld16/wave)
#pragma unroll
  for (int it = 0; it < 16; ++it) {
    int row = wv * 16 + it;
    int gr = g0 + row; if (gr >= lim) gr = lim - 1;
    int tok = list[gr];
    int slot = (l & 56) | ((l & 7) ^ (row & 7));
    gld16(xb + (size_t)tok * D_DIM + slot * 8, sA + row * 512);
  }
  __syncthreads();   // the ONLY barrier

  int cloc = l & 15, rb = (l >> 4) * 4;
#pragma unroll
  for (int g = 0; g < 4; ++g) {
    int np = npg * 4 + g;
    const unsigned short* b1p = w1f + ((size_t)(e * 128 + np * 2 + wc) * 16) * 512 + l * 8;
    const unsigned short* b3p = w3f + ((size_t)(e * 128 + np * 2 + wc) * 16) * 512 + l * 8;
    f32x4 au[2], av[2];
#pragma unroll
    for (int i = 0; i < 2; ++i) {
      au[i] = (f32x4){0.f, 0.f, 0.f, 0.f};
      av[i] = (f32x4){0.f, 0.f, 0.f, 0.f};
    }
#pragma unroll
    for (int kf = 0; kf < 16; ++kf) {
      short8 b1 = *(const short8*)(b1p + (size_t)kf * 512);
      short8 b3 = *(const short8*)(b3p + (size_t)kf * 512);
      short8 a[2];
#pragma unroll
      for (int i = 0; i < 2; ++i) {
        int r = wr * 32 + i * 16 + (l & 15);
        int slot = kf * 4 + (l >> 4);
        int swz = (slot & 56) | ((slot & 7) ^ (r & 7));
        a[i] = *(const short8*)(sA + r * 512 + swz * 8);
      }
#pragma unroll
      for (int i = 0; i < 2; ++i) {
        au[i] = __builtin_amdgcn_mfma_f32_16x16x32_bf16(a[i], b1, au[i], 0, 0, 0);
        av[i] = __builtin_amdgcn_mfma_f32_16x16x32_bf16(a[i], b3, av[i], 0, 0, 0);
      }
    }
    int col = np * 32 + wc * 16 + cloc;
#pragma unroll
    for (int i = 0; i < 2; ++i)
#pragma unroll
      for (int r = 0; r < 4; ++r) {
        int gr = g0 + wr * 32 + i * 16 + rb + r;
        if (gr < lim) {
          float uu = au[i][r], vv = av[i][r];
          float hh = (uu / (1.f + expf(-uu))) * vv;
          hbuf[(size_t)gr * F_DIM + col] = f2bf(hh);
        }
      }
  }
}

// ---- pass 2: y = h @ W2, out[tok]=w*y; BM=64 BN=64, A dbuf + B ping-pong (R5 form) ----
__global__ __launch_bounds__(256, 3) void k_ffn2(const unsigned short* __restrict__ hbuf,
                                                 const unsigned short* __restrict__ w2f,
                                                 const int* __restrict__ cntp,
                                                 const int* __restrict__ basep,
                                                 const int* __restrict__ list,
                                                 const int* __restrict__ tl1,
                                                 const int* __restrict__ ntl,
                                                 const float* __restrict__ wbuf,
                                                 float* __restrict__ out) {
  if ((int)blockIdx.x >= ntl[0]) return;
  int pk = tl1[blockIdx.x];
  int e = pk >> 16, g0 = pk & 0xffff;
  int lim = basep[e] + cntp[e];
  int nt = blockIdx.y;
  __shared__ unsigned short sA[2 * 8192];   // 2 x 16 KB chunks [64][128], swizzled
  int tid = threadIdx.x, wv = tid >> 6, l = tid & 63;
  int wr = wv >> 1, wc = wv & 1;

  auto stage = [&](int buf, int ck) {
#pragma unroll
    for (int it = 0; it < 4; ++it) {
      int row0 = it * 16 + wv * 4;             // wave-uniform
      int row = row0 + (l >> 4);
      int gr = g0 + row; if (gr > T_TOK - 1) gr = T_TOK - 1;
      int sl = (l & 8) | ((l & 7) ^ (row & 7));
      gld16(hbuf + (size_t)gr * F_DIM + ck * 128 + sl * 8, sA + buf * 8192 + row0 * 128);
    }
  };

  const unsigned short* b2p = w2f + ((size_t)(e * 32 + nt * 4 + wc * 2) * 64) * 512 + l * 8;

  short8 Ba[8], Bb[8];
  auto loadB = [&](short8* B, int ck) {
#pragma unroll
    for (int kk = 0; kk < 4; ++kk)
#pragma unroll
      for (int j = 0; j < 2; ++j)
        B[kk * 2 + j] = *(const short8*)(b2p + (size_t)(j * 64 + ck * 4 + kk) * 512);
  };

  f32x4 acc[2][2];
#pragma unroll
  for (int i = 0; i < 2; ++i)
#pragma unroll
    for (int j = 0; j < 2; ++j) acc[i][j] = (f32x4){0.f, 0.f, 0.f, 0.f};

  auto compute = [&](const short8* B, int cur) {
#pragma unroll
    for (int kk = 0; kk < 4; ++kk) {
      short8 a[2];
#pragma unroll
      for (int i = 0; i < 2; ++i) {
        int r = wr * 32 + i * 16 + (l & 15);
        int slot = kk * 4 + (l >> 4);
        int swz = (slot & 8) | ((slot & 7) ^ (r & 7));
        a[i] = *(const short8*)(sA + cur * 8192 + r * 128 + swz * 8);
      }
      acc[0][0] = __builtin_amdgcn_mfma_f32_16x16x32_bf16(a[0], B[kk * 2 + 0], acc[0][0], 0, 0, 0);
      acc[0][1] = __builtin_amdgcn_mfma_f32_16x16x32_bf16(a[0], B[kk * 2 + 1], acc[0][1], 0, 0, 0);
      acc[1][0] = __builtin_amdgcn_mfma_f32_16x16x32_bf16(a[1], B[kk * 2 + 0], acc[1][0], 0, 0, 0);
      acc[1][1] = __builtin_amdgcn_mfma_f32_16x16x32_bf16(a[1], B[kk * 2 + 1], acc[1][1], 0, 0, 0);
    }
  };

  stage(0, 0);
  loadB(Ba, 0);
  __syncthreads();
  int cur = 0;
  for (int ck = 0; ck < 16; ck += 2) {
    stage(cur ^ 1, ck + 1);
    loadB(Bb, ck + 1);
    compute(Ba, cur);
    __syncthreads();
    cur ^= 1;
    if (ck + 2 < 16) {
      stage(cur ^ 1, ck + 2);
      loadB(Ba, ck + 2);
    }
    compute(Bb, cur);
    __syncthreads();
    cur ^= 1;
  }

  int cloc = l & 15, rb = (l >> 4) * 4;
#pragma unroll
  for (int i = 0; i < 2; ++i)
#pragma unroll
    for (int j = 0; j < 2; ++j)
#pragma unroll
      for (int r = 0; r < 4; ++r) {
        int gr = g0 + wr * 32 + i * 16 + rb + r;
        if (gr < lim) {
          int tok = list[gr];
          out[(size_t)tok * D_DIM + nt * 64 + wc * 32 + j * 16 + cloc] = wbuf[tok] * acc[i][j][r];
        }
      }
}

// ---------------- launch ----------------
extern "C" void kernel_launch(void* const* d_in, const int* in_sizes, int n_in,
                              void* d_out, int out_size, void* d_ws, size_t ws_size,
                              hipStream_t stream) {
  const float* x  = (const float*)d_in[0];
  const float* Wg = (const float*)d_in[1];
  const float* W1 = (const float*)d_in[2];
  const float* W2 = (const float*)d_in[3];
  const float* W3 = (const float*)d_in[4];
  float* out = (float*)d_out;
  char* ws = (char*)d_ws;

  int*            jbuf  = (int*)(ws + 0);
  float*          wbuf  = (float*)(ws + 8192);
  int*            cntp  = (int*)(ws + 16384);
  int*            basep = (int*)(ws + 16448);
  int*            list  = (int*)(ws + 16640);      // int[2048]
  int*            tl1   = (int*)(ws + 24832);      // int[40]
  int*            ntl   = (int*)(ws + 25600);      // int[2]
  unsigned short* xb    = (unsigned short*)(ws + 32768);                          // bf16 [2048][512]
  unsigned short* w1f   = (unsigned short*)(ws + 32768 + 2097152);                // frag [8][128][16][64][8]
  unsigned short* w3f   = (unsigned short*)(ws + 32768 + 2097152 + 16777216);
  unsigned short* w2f   = (unsigned short*)(ws + 32768 + 2097152 + 2 * 16777216); // frag [8][32][64][64][8]
  unsigned short* hbuf  = (unsigned short*)(ws + 32768 + 2097152 + 3 * 16777216); // bf16 [2048][2048]

  k_route<<<dim3(256), dim3(256), 0, stream>>>(x, Wg, jbuf, wbuf, xb);
  k_bucket<<<dim3(1), dim3(256), 0, stream>>>(jbuf, cntp, basep, list, tl1, ntl);
  k_wfrag<<<dim3(32, 8, 16), dim3(256), 0, stream>>>(W1, W3, w1f, w3f, 512, 2048);
  k_wfrag<<<dim3(8, 32, 8), dim3(256), 0, stream>>>(W2, W2, w2f, w2f, 2048, 512);
  k_ffn1<<<dim3(MAXT1, 16), dim3(256), 0, stream>>>(xb, w1f, w3f, cntp, basep, list, tl1, ntl, hbuf);
  k_ffn2<<<dim3(MAXT1, 8), dim3(256), 0, stream>>>(hbuf, w2f, cntp, basep, list, tl1, ntl, wbuf, out);
}

// Round 10
// 88.718 us; speedup vs baseline: 1.3785x; 1.2053x over previous
//
#include <hip/hip_runtime.h>
#include <hip/hip_bf16.h>
#include <math.h>

typedef __attribute__((ext_vector_type(8))) short short8;
typedef __attribute__((ext_vector_type(4))) float f32x4;

#define T_TOK 2048
#define D_DIM 512
#define F_DIM 2048
#define E_NUM 8
#define MAXT1 40   // == sum_e ceil(cnt_e/64) upper bound (32 + 7 rounding)

__device__ __forceinline__ unsigned short f2bf(float f) {
  union { float f; unsigned u; } c; c.f = f;
  unsigned u = c.u;
  return (unsigned short)((u + 0x7fffu + ((u >> 16) & 1u)) >> 16);
}

__device__ __forceinline__ void gld16(const void* g, void* l) {
  __builtin_amdgcn_global_load_lds((const __attribute__((address_space(1))) int*)g,
                                   (__attribute__((address_space(3))) int*)l, 16, 0, 0);
}

// ---- routing: logits (32-way K-split) + top-2 + weight; also converts x->bf16 ----
__global__ __launch_bounds__(256) void k_route(const float* __restrict__ x,
                                               const float* __restrict__ Wg,
                                               int* __restrict__ jbuf,
                                               float* __restrict__ wbuf,
                                               unsigned short* __restrict__ xb) {
  int gid = blockIdx.x * 256 + threadIdx.x;
  int t = gid >> 5, seg = gid & 31;
  const float* xp = x + (size_t)t * D_DIM + seg * 16;
  unsigned short* xo = xb + (size_t)t * D_DIM + seg * 16;
  float acc[8];
#pragma unroll
  for (int e = 0; e < 8; ++e) acc[e] = 0.f;
#pragma unroll
  for (int i = 0; i < 4; ++i) {
    float4 v = *(const float4*)(xp + i * 4);
    ushort4 o;
    o.x = f2bf(v.x); o.y = f2bf(v.y); o.z = f2bf(v.z); o.w = f2bf(v.w);
    *(ushort4*)(xo + i * 4) = o;
    const float* xs = (const float*)&v;
#pragma unroll
    for (int q = 0; q < 4; ++q) {
      int d = seg * 16 + i * 4 + q;
      const float4* wr = (const float4*)(Wg + (size_t)d * 8);
      float4 w0 = wr[0], w1 = wr[1];
      acc[0] += xs[q] * w0.x; acc[1] += xs[q] * w0.y;
      acc[2] += xs[q] * w0.z; acc[3] += xs[q] * w0.w;
      acc[4] += xs[q] * w1.x; acc[5] += xs[q] * w1.y;
      acc[6] += xs[q] * w1.z; acc[7] += xs[q] * w1.w;
    }
  }
#pragma unroll
  for (int off = 1; off < 32; off <<= 1)
#pragma unroll
    for (int e = 0; e < 8; ++e) acc[e] += __shfl_xor(acc[e], off);
  if (seg == 0) {
    float l0 = -1e30f, l1 = -1e30f; int i0 = 0, i1 = 0;
#pragma unroll
    for (int e = 0; e < 8; ++e) {
      float l = acc[e];
      if (l > l0) { l1 = l0; i1 = i0; l0 = l; i0 = e; }
      else if (l > l1) { l1 = l; i1 = e; }
    }
    int j; float w;
    if (i0 > i1) { j = i0; w = 1.f / (1.f + expf(l1 - l0)); }
    else         { j = i1; w = 1.f / (1.f + expf(l0 - l1)); }
    jbuf[t] = j; wbuf[t] = w;
  }
}

// ---- bucket: counts, bases, compact token list, compact tile list (BM=64) ----
__global__ __launch_bounds__(256) void k_bucket(const int* __restrict__ jbuf,
                                                int* __restrict__ cntp,
                                                int* __restrict__ basep,
                                                int* __restrict__ list,
                                                int* __restrict__ tl1,
                                                int* __restrict__ ntl) {
  __shared__ int scnt[8], scur[8];
  int tid = threadIdx.x;
  if (tid < 8) scnt[tid] = 0;
  __syncthreads();
  for (int t = tid; t < T_TOK; t += 256) atomicAdd(&scnt[jbuf[t]], 1);
  __syncthreads();
  if (tid == 0) {
    int run = 0;
    for (int e = 0; e < 8; ++e) {
      cntp[e] = scnt[e]; basep[e] = run; scur[e] = run;
      run += scnt[e];
    }
    int n1 = 0, bb = 0;
    for (int e = 0; e < 8; ++e) {
      for (int m = 0; m < scnt[e]; m += 64) tl1[n1++] = (e << 16) | (bb + m);
      bb += scnt[e];
    }
    ntl[0] = n1;
  }
  __syncthreads();
  for (int t = tid; t < T_TOK; t += 256) {
    int j = jbuf[t];
    int p = atomicAdd(&scur[j], 1);
    list[p] = t;
  }
}

// ---- weight reformat: [Z][K][N] f32 -> fragment-major bf16 [Z][N/16][K/32][64][8] ----
__global__ __launch_bounds__(256) void k_wfrag(const float* __restrict__ inA,
                                               const float* __restrict__ inB,
                                               unsigned short* __restrict__ outA,
                                               unsigned short* __restrict__ outB,
                                               int K, int N) {
  __shared__ float tile[64][65];
  int z = blockIdx.z;
  const float* in; unsigned short* out;
  size_t zsz = (size_t)(K / 32) * (N / 16) * 512;
  if (z < 8) { in = inA + (size_t)z * K * N;       out = outA + (size_t)z * zsz; }
  else       { in = inB + (size_t)(z - 8) * K * N; out = outB + (size_t)(z - 8) * zsz; }
  int n0 = blockIdx.x * 64, k0 = blockIdx.y * 64;
  int tid = threadIdx.x;
  int lr = tid >> 4, lc = tid & 15;
#pragma unroll
  for (int it = 0; it < 4; ++it) {
    int row = it * 16 + lr;
    float4 v = *(const float4*)(in + (size_t)(k0 + row) * N + n0 + lc * 4);
    tile[row][lc * 4 + 0] = v.x;
    tile[row][lc * 4 + 1] = v.y;
    tile[row][lc * 4 + 2] = v.z;
    tile[row][lc * 4 + 3] = v.w;
  }
  __syncthreads();
  int wv = tid >> 6, l = tid & 63;
#pragma unroll
  for (int q = 0; q < 2; ++q) {
    int fid = wv * 2 + q;
    int nb = fid >> 1, kb = fid & 1;
    short8 o;
#pragma unroll
    for (int j = 0; j < 8; ++j)
      o[j] = (short)f2bf(tile[kb * 32 + (l >> 4) * 8 + j][nb * 16 + (l & 15)]);
    unsigned short* op = out + (((size_t)(n0 / 16 + nb) * (K / 32)) + (k0 / 32 + kb)) * 512 + l * 8;
    *(short8*)op = o;
  }
}

// ---- pass 1: A staged once; 4 panels with half-K register ping-pong B prefetch ----
__global__ __launch_bounds__(256, 2) void k_ffn1(const unsigned short* __restrict__ xb,
                                                 const unsigned short* __restrict__ w1f,
                                                 const unsigned short* __restrict__ w3f,
                                                 const int* __restrict__ cntp,
                                                 const int* __restrict__ basep,
                                                 const int* __restrict__ list,
                                                 const int* __restrict__ tl1,
                                                 const int* __restrict__ ntl,
                                                 unsigned short* __restrict__ hbuf) {
  int L = blockIdx.x;
  int b = (L & 7) * 80 + (L >> 3);     // XCD swizzle: XCD g owns logical ids [80g,80g+80)
  int x = b % 40, y = b / 40;          // x: m-tile, y: 128-col panel group
  if (x >= ntl[0]) return;
  int pk = tl1[x];
  int e = pk >> 16, g0 = pk & 0xffff;
  int lim = basep[e] + cntp[e];
  __shared__ unsigned short sA[64 * 512];   // 64 KB, XOR-swizzled 16B slots
  int tid = threadIdx.x, wv = tid >> 6, l = tid & 63;
  int wr = wv >> 1, wc = wv & 1;

  // one-time A stage: wave wv stages rows wv*16..+15
#pragma unroll
  for (int it = 0; it < 16; ++it) {
    int row = wv * 16 + it;
    int gr = g0 + row; if (gr >= lim) gr = lim - 1;
    int tok = list[gr];
    int slot = (l & 56) | ((l & 7) ^ (row & 7));
    gld16(xb + (size_t)tok * D_DIM + slot * 8, sA + row * 512);
  }

  // B fragment bases: nb = y*8 + g*2 + wc; frag (nb, kf) at (nb*16+kf)*512
  const unsigned short* w1b = w1f + ((size_t)(e * 128 + y * 8 + wc) * 16) * 512 + l * 8;
  const unsigned short* w3b = w3f + ((size_t)(e * 128 + y * 8 + wc) * 16) * 512 + l * 8;

  short8 P1[8], P3[8], Q1[8], Q3[8];
  auto loadS = [&](short8* r1, short8* r3, int s) {   // s = panel*2 + half
    int g = s >> 1, h = s & 1;
    const unsigned short* p1 = w1b + ((size_t)(g * 32 + h * 8)) * 512;
    const unsigned short* p3 = w3b + ((size_t)(g * 32 + h * 8)) * 512;
#pragma unroll
    for (int q = 0; q < 8; ++q) {
      r1[q] = *(const short8*)(p1 + (size_t)q * 512);
      r3[q] = *(const short8*)(p3 + (size_t)q * 512);
    }
  };

  f32x4 au[2], av[2];
  auto halfC = [&](const short8* r1, const short8* r3, int h) {
#pragma unroll
    for (int q = 0; q < 8; ++q) {
      int kf = h * 8 + q;
      short8 a[2];
#pragma unroll
      for (int i = 0; i < 2; ++i) {
        int r = wr * 32 + i * 16 + (l & 15);
        int slot = kf * 4 + (l >> 4);
        int swz = (slot & 56) | ((slot & 7) ^ (r & 7));
        a[i] = *(const short8*)(sA + r * 512 + swz * 8);
      }
#pragma unroll
      for (int i = 0; i < 2; ++i) {
        au[i] = __builtin_amdgcn_mfma_f32_16x16x32_bf16(a[i], r1[q], au[i], 0, 0, 0);
        av[i] = __builtin_amdgcn_mfma_f32_16x16x32_bf16(a[i], r3[q], av[i], 0, 0, 0);
      }
    }
  };

  loadS(P1, P3, 0);
  __syncthreads();   // sA ready (the only barrier)

  int cloc = l & 15, rb = (l >> 4) * 4;
#pragma unroll
  for (int gp = 0; gp < 4; ++gp) {
#pragma unroll
    for (int i = 0; i < 2; ++i) {
      au[i] = (f32x4){0.f, 0.f, 0.f, 0.f};
      av[i] = (f32x4){0.f, 0.f, 0.f, 0.f};
    }
    loadS(Q1, Q3, gp * 2 + 1);        // prefetch 2nd half while computing 1st
    halfC(P1, P3, 0);
    if (gp < 3) loadS(P1, P3, gp * 2 + 2);   // prefetch next panel's 1st half
    halfC(Q1, Q3, 1);
    int col = (y * 4 + gp) * 32 + wc * 16 + cloc;
#pragma unroll
    for (int i = 0; i < 2; ++i)
#pragma unroll
      for (int r = 0; r < 4; ++r) {
        int gr = g0 + wr * 32 + i * 16 + rb + r;
        if (gr < lim) {
          float uu = au[i][r], vv = av[i][r];
          float hh = (uu / (1.f + expf(-uu))) * vv;
          hbuf[(size_t)gr * F_DIM + col] = f2bf(hh);
        }
      }
  }
}

// ---- pass 2: y = h @ W2; BM=64 BN=32 BK=128, A dbuf + B ping-pong, XCD swizzle ----
__global__ __launch_bounds__(256, 3) void k_ffn2(const unsigned short* __restrict__ hbuf,
                                                 const unsigned short* __restrict__ w2f,
                                                 const int* __restrict__ cntp,
                                                 const int* __restrict__ basep,
                                                 const int* __restrict__ list,
                                                 const int* __restrict__ tl1,
                                                 const int* __restrict__ ntl,
                                                 const float* __restrict__ wbuf,
                                                 float* __restrict__ out) {
  int L = blockIdx.x;
  int b = (L & 7) * 80 + (L >> 3);
  int x = b % 40, nt = b / 40;         // x: m-tile, nt: 32-col d-panel
  if (x >= ntl[0]) return;
  int pk = tl1[x];
  int e = pk >> 16, g0 = pk & 0xffff;
  int lim = basep[e] + cntp[e];
  __shared__ unsigned short sA[2 * 8192];   // 2 x 16 KB chunks [64][128], swizzled
  int tid = threadIdx.x, wv = tid >> 6, l = tid & 63;
  int wr = wv >> 1, wc = wv & 1;

  auto stage = [&](int buf, int ck) {
#pragma unroll
    for (int it = 0; it < 4; ++it) {
      int row0 = it * 16 + wv * 4;             // wave-uniform
      int row = row0 + (l >> 4);
      int gr = g0 + row; if (gr > T_TOK - 1) gr = T_TOK - 1;
      int sl = (l & 8) | ((l & 7) ^ (row & 7));
      gld16(hbuf + (size_t)gr * F_DIM + ck * 128 + sl * 8, sA + buf * 8192 + row0 * 128);
    }
  };

  // w2f frag (nb, kf) at (nb*64 + kf)*512; nb = nt*2 + wc
  const unsigned short* b2p = w2f + ((size_t)(e * 32 + nt * 2 + wc) * 64) * 512 + l * 8;

  short8 Ba[4], Bb[4];
  auto loadB = [&](short8* B, int ck) {
#pragma unroll
    for (int kk = 0; kk < 4; ++kk)
      B[kk] = *(const short8*)(b2p + (size_t)(ck * 4 + kk) * 512);
  };

  f32x4 acc[2];
  acc[0] = (f32x4){0.f, 0.f, 0.f, 0.f};
  acc[1] = (f32x4){0.f, 0.f, 0.f, 0.f};

  auto compute = [&](const short8* B, int cur) {
#pragma unroll
    for (int kk = 0; kk < 4; ++kk) {
      short8 a[2];
#pragma unroll
      for (int i = 0; i < 2; ++i) {
        int r = wr * 32 + i * 16 + (l & 15);
        int slot = kk * 4 + (l >> 4);
        int swz = (slot & 8) | ((slot & 7) ^ (r & 7));
        a[i] = *(const short8*)(sA + cur * 8192 + r * 128 + swz * 8);
      }
      acc[0] = __builtin_amdgcn_mfma_f32_16x16x32_bf16(a[0], B[kk], acc[0], 0, 0, 0);
      acc[1] = __builtin_amdgcn_mfma_f32_16x16x32_bf16(a[1], B[kk], acc[1], 0, 0, 0);
    }
  };

  stage(0, 0);
  loadB(Ba, 0);
  __syncthreads();
  int cur = 0;
  for (int ck = 0; ck < 16; ck += 2) {
    stage(cur ^ 1, ck + 1);
    loadB(Bb, ck + 1);
    compute(Ba, cur);
    __syncthreads();
    cur ^= 1;
    if (ck + 2 < 16) {
      stage(cur ^ 1, ck + 2);
      loadB(Ba, ck + 2);
    }
    compute(Bb, cur);
    __syncthreads();
    cur ^= 1;
  }

  int cloc = l & 15, rb = (l >> 4) * 4;
#pragma unroll
  for (int i = 0; i < 2; ++i)
#pragma unroll
    for (int r = 0; r < 4; ++r) {
      int gr = g0 + wr * 32 + i * 16 + rb + r;
      if (gr < lim) {
        int tok = list[gr];
        out[(size_t)tok * D_DIM + nt * 32 + wc * 16 + cloc] = wbuf[tok] * acc[i][r];
      }
    }
}

// ---------------- launch ----------------
extern "C" void kernel_launch(void* const* d_in, const int* in_sizes, int n_in,
                              void* d_out, int out_size, void* d_ws, size_t ws_size,
                              hipStream_t stream) {
  const float* x  = (const float*)d_in[0];
  const float* Wg = (const float*)d_in[1];
  const float* W1 = (const float*)d_in[2];
  const float* W2 = (const float*)d_in[3];
  const float* W3 = (const float*)d_in[4];
  float* out = (float*)d_out;
  char* ws = (char*)d_ws;

  int*            jbuf  = (int*)(ws + 0);
  float*          wbuf  = (float*)(ws + 8192);
  int*            cntp  = (int*)(ws + 16384);
  int*            basep = (int*)(ws + 16448);
  int*            list  = (int*)(ws + 16640);      // int[2048]
  int*            tl1   = (int*)(ws + 24832);      // int[40]
  int*            ntl   = (int*)(ws + 25600);      // int[2]
  unsigned short* xb    = (unsigned short*)(ws + 32768);                          // bf16 [2048][512]
  unsigned short* w1f   = (unsigned short*)(ws + 32768 + 2097152);                // frag [8][128][16][64][8]
  unsigned short* w3f   = (unsigned short*)(ws + 32768 + 2097152 + 16777216);
  unsigned short* w2f   = (unsigned short*)(ws + 32768 + 2097152 + 2 * 16777216); // frag [8][32][64][64][8]
  unsigned short* hbuf  = (unsigned short*)(ws + 32768 + 2097152 + 3 * 16777216); // bf16 [2048][2048]

  k_route<<<dim3(256), dim3(256), 0, stream>>>(x, Wg, jbuf, wbuf, xb);
  k_bucket<<<dim3(1), dim3(256), 0, stream>>>(jbuf, cntp, basep, list, tl1, ntl);
  k_wfrag<<<dim3(32, 8, 16), dim3(256), 0, stream>>>(W1, W3, w1f, w3f, 512, 2048);
  k_wfrag<<<dim3(8, 32, 8), dim3(256), 0, stream>>>(W2, W2, w2f, w2f, 2048, 512);
  k_ffn1<<<dim3(640), dim3(256), 0, stream>>>(xb, w1f, w3f, cntp, basep, list, tl1, ntl, hbuf);
  k_ffn2<<<dim3(640), dim3(256), 0, stream>>>(hbuf, w2f, cntp, basep, list, tl1, ntl, wbuf, out);
}

// Round 11
// 82.922 us; speedup vs baseline: 1.4748x; 1.0699x over previous
//
#include <hip/hip_runtime.h>
#include <hip/hip_bf16.h>
#include <math.h>

typedef __attribute__((ext_vector_type(8))) short short8;
typedef __attribute__((ext_vector_type(4))) float f32x4;

#define T_TOK 2048
#define D_DIM 512
#define F_DIM 2048
#define E_NUM 8
#define MAXT1 40   // == sum_e ceil(cnt_e/64) upper bound (32 + 7 rounding)

__device__ __forceinline__ unsigned short f2bf(float f) {
  union { float f; unsigned u; } c; c.f = f;
  unsigned u = c.u;
  return (unsigned short)((u + 0x7fffu + ((u >> 16) & 1u)) >> 16);
}

__device__ __forceinline__ void gld16(const void* g, void* l) {
  __builtin_amdgcn_global_load_lds((const __attribute__((address_space(1))) int*)g,
                                   (__attribute__((address_space(3))) int*)l, 16, 0, 0);
}

// ---- prep mega-kernel: route (blocks 0..255) + wfrag1 (256..4351) + wfrag2 (4352..6399) ----
__global__ __launch_bounds__(256) void k_prep(const float* __restrict__ xin,
                                              const float* __restrict__ Wg,
                                              const float* __restrict__ W1,
                                              const float* __restrict__ W3,
                                              const float* __restrict__ W2,
                                              int* __restrict__ jbuf,
                                              float* __restrict__ wbuf,
                                              unsigned short* __restrict__ xb,
                                              unsigned short* __restrict__ w1f,
                                              unsigned short* __restrict__ w3f,
                                              unsigned short* __restrict__ w2f) {
  __shared__ float tile[64][65];
  int bz = blockIdx.x, tid = threadIdx.x;

  if (bz < 256) {
    // ---- routing: logits (32-way K-split) + top-2 + weight; converts x->bf16 ----
    int gid = bz * 256 + tid;
    int t = gid >> 5, seg = gid & 31;
    const float* xp = xin + (size_t)t * D_DIM + seg * 16;
    unsigned short* xo = xb + (size_t)t * D_DIM + seg * 16;
    float acc[8];
#pragma unroll
    for (int e = 0; e < 8; ++e) acc[e] = 0.f;
#pragma unroll
    for (int i = 0; i < 4; ++i) {
      float4 v = *(const float4*)(xp + i * 4);
      ushort4 o;
      o.x = f2bf(v.x); o.y = f2bf(v.y); o.z = f2bf(v.z); o.w = f2bf(v.w);
      *(ushort4*)(xo + i * 4) = o;
      const float* xs = (const float*)&v;
#pragma unroll
      for (int q = 0; q < 4; ++q) {
        int d = seg * 16 + i * 4 + q;
        const float4* wr = (const float4*)(Wg + (size_t)d * 8);
        float4 w0 = wr[0], w1 = wr[1];
        acc[0] += xs[q] * w0.x; acc[1] += xs[q] * w0.y;
        acc[2] += xs[q] * w0.z; acc[3] += xs[q] * w0.w;
        acc[4] += xs[q] * w1.x; acc[5] += xs[q] * w1.y;
        acc[6] += xs[q] * w1.z; acc[7] += xs[q] * w1.w;
      }
    }
#pragma unroll
    for (int off = 1; off < 32; off <<= 1)
#pragma unroll
      for (int e = 0; e < 8; ++e) acc[e] += __shfl_xor(acc[e], off);
    if (seg == 0) {
      float l0 = -1e30f, l1 = -1e30f; int i0 = 0, i1 = 0;
#pragma unroll
      for (int e = 0; e < 8; ++e) {
        float l = acc[e];
        if (l > l0) { l1 = l0; i1 = i0; l0 = l; i0 = e; }
        else if (l > l1) { l1 = l; i1 = e; }
      }
      int j; float w;
      if (i0 > i1) { j = i0; w = 1.f / (1.f + expf(l1 - l0)); }
      else         { j = i1; w = 1.f / (1.f + expf(l0 - l1)); }
      jbuf[t] = j; wbuf[t] = w;
    }
    return;
  }

  // ---- weight reformat: [K][N] f32 -> fragment-major bf16 [N/16][K/32][64][8] ----
  const float* in; unsigned short* out;
  int K, N, n0, k0;
  if (bz < 4352) {                 // wfrag1: W1/W3, K=512, N=2048
    int idx = bz - 256;            // [0,4096)
    int z = idx >> 8, rem = idx & 255;
    K = 512; N = 2048;
    n0 = (rem & 31) * 64; k0 = (rem >> 5) * 64;
    size_t zsz = (size_t)(K / 32) * (N / 16) * 512;
    if (z < 8) { in = W1 + (size_t)z * K * N;       out = w1f + (size_t)z * zsz; }
    else       { in = W3 + (size_t)(z - 8) * K * N; out = w3f + (size_t)(z - 8) * zsz; }
  } else {                         // wfrag2: W2, K=2048, N=512
    int idx = bz - 4352;           // [0,2048)
    int z = idx >> 8, rem = idx & 255;
    K = 2048; N = 512;
    n0 = (rem & 7) * 64; k0 = (rem >> 3) * 64;
    size_t zsz = (size_t)(K / 32) * (N / 16) * 512;
    in = W2 + (size_t)z * K * N; out = w2f + (size_t)z * zsz;
  }
  int lr = tid >> 4, lc = tid & 15;
#pragma unroll
  for (int it = 0; it < 4; ++it) {
    int row = it * 16 + lr;
    float4 v = *(const float4*)(in + (size_t)(k0 + row) * N + n0 + lc * 4);
    tile[row][lc * 4 + 0] = v.x;
    tile[row][lc * 4 + 1] = v.y;
    tile[row][lc * 4 + 2] = v.z;
    tile[row][lc * 4 + 3] = v.w;
  }
  __syncthreads();
  int wv = tid >> 6, l = tid & 63;
#pragma unroll
  for (int q = 0; q < 2; ++q) {
    int fid = wv * 2 + q;
    int nb = fid >> 1, kb = fid & 1;
    short8 o;
#pragma unroll
    for (int j = 0; j < 8; ++j)
      o[j] = (short)f2bf(tile[kb * 32 + (l >> 4) * 8 + j][nb * 16 + (l & 15)]);
    unsigned short* op = out + (((size_t)(n0 / 16 + nb) * (K / 32)) + (k0 / 32 + kb)) * 512 + l * 8;
    *(short8*)op = o;
  }
}

// ---- bucket: counts, bases, compact token list, compact tile list (BM=64) ----
__global__ __launch_bounds__(256) void k_bucket(const int* __restrict__ jbuf,
                                                int* __restrict__ cntp,
                                                int* __restrict__ basep,
                                                int* __restrict__ list,
                                                int* __restrict__ tl1,
                                                int* __restrict__ ntl) {
  __shared__ int scnt[8], scur[8];
  int tid = threadIdx.x;
  if (tid < 8) scnt[tid] = 0;
  __syncthreads();
  for (int t = tid; t < T_TOK; t += 256) atomicAdd(&scnt[jbuf[t]], 1);
  __syncthreads();
  if (tid == 0) {
    int run = 0;
    for (int e = 0; e < 8; ++e) {
      cntp[e] = scnt[e]; basep[e] = run; scur[e] = run;
      run += scnt[e];
    }
    int n1 = 0, bb = 0;
    for (int e = 0; e < 8; ++e) {
      for (int m = 0; m < scnt[e]; m += 64) tl1[n1++] = (e << 16) | (bb + m);
      bb += scnt[e];
    }
    ntl[0] = n1;
  }
  __syncthreads();
  for (int t = tid; t < T_TOK; t += 256) {
    int j = jbuf[t];
    int p = atomicAdd(&scur[j], 1);
    list[p] = t;
  }
}

// ---- pass 1: A staged once; 4 panels with half-K register ping-pong B prefetch ----
__global__ __launch_bounds__(256, 2) void k_ffn1(const unsigned short* __restrict__ xb,
                                                 const unsigned short* __restrict__ w1f,
                                                 const unsigned short* __restrict__ w3f,
                                                 const int* __restrict__ cntp,
                                                 const int* __restrict__ basep,
                                                 const int* __restrict__ list,
                                                 const int* __restrict__ tl1,
                                                 const int* __restrict__ ntl,
                                                 unsigned short* __restrict__ hbuf) {
  int L = blockIdx.x;
  int b = (L & 7) * 80 + (L >> 3);     // XCD owns 2 col-groups x all m-tiles
  int x = b % 40, y = b / 40;          // x: m-tile, y: 128-col panel group
  if (x >= ntl[0]) return;
  int pk = tl1[x];
  int e = pk >> 16, g0 = pk & 0xffff;
  int lim = basep[e] + cntp[e];
  __shared__ unsigned short sA[64 * 512];   // 64 KB, XOR-swizzled 16B slots
  int tid = threadIdx.x, wv = tid >> 6, l = tid & 63;
  int wr = wv >> 1, wc = wv & 1;

  // one-time A stage: wave wv stages rows wv*16..+15
#pragma unroll
  for (int it = 0; it < 16; ++it) {
    int row = wv * 16 + it;
    int gr = g0 + row; if (gr >= lim) gr = lim - 1;
    int tok = list[gr];
    int slot = (l & 56) | ((l & 7) ^ (row & 7));
    gld16(xb + (size_t)tok * D_DIM + slot * 8, sA + row * 512);
  }

  const unsigned short* w1b = w1f + ((size_t)(e * 128 + y * 8 + wc) * 16) * 512 + l * 8;
  const unsigned short* w3b = w3f + ((size_t)(e * 128 + y * 8 + wc) * 16) * 512 + l * 8;

  short8 P1[8], P3[8], Q1[8], Q3[8];
  auto loadS = [&](short8* r1, short8* r3, int s) {   // s = panel*2 + half
    int g = s >> 1, h = s & 1;
    const unsigned short* p1 = w1b + ((size_t)(g * 32 + h * 8)) * 512;
    const unsigned short* p3 = w3b + ((size_t)(g * 32 + h * 8)) * 512;
#pragma unroll
    for (int q = 0; q < 8; ++q) {
      r1[q] = *(const short8*)(p1 + (size_t)q * 512);
      r3[q] = *(const short8*)(p3 + (size_t)q * 512);
    }
  };

  f32x4 au[2], av[2];
  auto halfC = [&](const short8* r1, const short8* r3, int h) {
#pragma unroll
    for (int q = 0; q < 8; ++q) {
      int kf = h * 8 + q;
      short8 a[2];
#pragma unroll
      for (int i = 0; i < 2; ++i) {
        int r = wr * 32 + i * 16 + (l & 15);
        int slot = kf * 4 + (l >> 4);
        int swz = (slot & 56) | ((slot & 7) ^ (r & 7));
        a[i] = *(const short8*)(sA + r * 512 + swz * 8);
      }
#pragma unroll
      for (int i = 0; i < 2; ++i) {
        au[i] = __builtin_amdgcn_mfma_f32_16x16x32_bf16(a[i], r1[q], au[i], 0, 0, 0);
        av[i] = __builtin_amdgcn_mfma_f32_16x16x32_bf16(a[i], r3[q], av[i], 0, 0, 0);
      }
    }
  };

  loadS(P1, P3, 0);
  __syncthreads();   // sA ready (the only barrier)

  int cloc = l & 15, rb = (l >> 4) * 4;
#pragma unroll
  for (int gp = 0; gp < 4; ++gp) {
#pragma unroll
    for (int i = 0; i < 2; ++i) {
      au[i] = (f32x4){0.f, 0.f, 0.f, 0.f};
      av[i] = (f32x4){0.f, 0.f, 0.f, 0.f};
    }
    loadS(Q1, Q3, gp * 2 + 1);        // prefetch 2nd half while computing 1st
    halfC(P1, P3, 0);
    if (gp < 3) loadS(P1, P3, gp * 2 + 2);   // prefetch next panel's 1st half
    halfC(Q1, Q3, 1);
    int col = (y * 4 + gp) * 32 + wc * 16 + cloc;
#pragma unroll
    for (int i = 0; i < 2; ++i)
#pragma unroll
      for (int r = 0; r < 4; ++r) {
        int gr = g0 + wr * 32 + i * 16 + rb + r;
        if (gr < lim) {
          float uu = au[i][r], vv = av[i][r];
          float hh = (uu / (1.f + expf(-uu))) * vv;
          hbuf[(size_t)gr * F_DIM + col] = f2bf(hh);
        }
      }
  }
}

// ---- pass 2: y = h @ W2; BM=64 BN=32 BK=128; XCD owns 5 m-tiles x all panels ----
__global__ __launch_bounds__(256, 3) void k_ffn2(const unsigned short* __restrict__ hbuf,
                                                 const unsigned short* __restrict__ w2f,
                                                 const int* __restrict__ cntp,
                                                 const int* __restrict__ basep,
                                                 const int* __restrict__ list,
                                                 const int* __restrict__ tl1,
                                                 const int* __restrict__ ntl,
                                                 const float* __restrict__ wbuf,
                                                 float* __restrict__ out) {
  int L = blockIdx.x;
  int c = L & 7, q = L >> 3;           // q in [0,80)
  int x = c * 5 + (q % 5);             // m-tile: XCD c owns [5c, 5c+5)
  int nt = q / 5;                      // 32-col d-panel [0,16)
  if (x >= ntl[0]) return;
  int pk = tl1[x];
  int e = pk >> 16, g0 = pk & 0xffff;
  int lim = basep[e] + cntp[e];
  __shared__ unsigned short sA[2 * 8192];   // 2 x 16 KB chunks [64][128], swizzled
  int tid = threadIdx.x, wv = tid >> 6, l = tid & 63;
  int wr = wv >> 1, wc = wv & 1;

  auto stage = [&](int buf, int ck) {
#pragma unroll
    for (int it = 0; it < 4; ++it) {
      int row0 = it * 16 + wv * 4;             // wave-uniform
      int row = row0 + (l >> 4);
      int gr = g0 + row; if (gr > T_TOK - 1) gr = T_TOK - 1;
      int sl = (l & 8) | ((l & 7) ^ (row & 7));
      gld16(hbuf + (size_t)gr * F_DIM + ck * 128 + sl * 8, sA + buf * 8192 + row0 * 128);
    }
  };

  // w2f frag (nb, kf) at (nb*64 + kf)*512; nb = nt*2 + wc
  const unsigned short* b2p = w2f + ((size_t)(e * 32 + nt * 2 + wc) * 64) * 512 + l * 8;

  short8 Ba[4], Bb[4];
  auto loadB = [&](short8* B, int ck) {
#pragma unroll
    for (int kk = 0; kk < 4; ++kk)
      B[kk] = *(const short8*)(b2p + (size_t)(ck * 4 + kk) * 512);
  };

  f32x4 acc[2];
  acc[0] = (f32x4){0.f, 0.f, 0.f, 0.f};
  acc[1] = (f32x4){0.f, 0.f, 0.f, 0.f};

  auto compute = [&](const short8* B, int cur) {
#pragma unroll
    for (int kk = 0; kk < 4; ++kk) {
      short8 a[2];
#pragma unroll
      for (int i = 0; i < 2; ++i) {
        int r = wr * 32 + i * 16 + (l & 15);
        int slot = kk * 4 + (l >> 4);
        int swz = (slot & 8) | ((slot & 7) ^ (r & 7));
        a[i] = *(const short8*)(sA + cur * 8192 + r * 128 + swz * 8);
      }
      acc[0] = __builtin_amdgcn_mfma_f32_16x16x32_bf16(a[0], B[kk], acc[0], 0, 0, 0);
      acc[1] = __builtin_amdgcn_mfma_f32_16x16x32_bf16(a[1], B[kk], acc[1], 0, 0, 0);
    }
  };

  stage(0, 0);
  loadB(Ba, 0);
  __syncthreads();
  int cur = 0;
  for (int ck = 0; ck < 16; ck += 2) {
    stage(cur ^ 1, ck + 1);
    loadB(Bb, ck + 1);
    compute(Ba, cur);
    __syncthreads();
    cur ^= 1;
    if (ck + 2 < 16) {
      stage(cur ^ 1, ck + 2);
      loadB(Ba, ck + 2);
    }
    compute(Bb, cur);
    __syncthreads();
    cur ^= 1;
  }

  int cloc = l & 15, rb = (l >> 4) * 4;
#pragma unroll
  for (int i = 0; i < 2; ++i)
#pragma unroll
    for (int r = 0; r < 4; ++r) {
      int gr = g0 + wr * 32 + i * 16 + rb + r;
      if (gr < lim) {
        int tok = list[gr];
        out[(size_t)tok * D_DIM + nt * 32 + wc * 16 + cloc] = wbuf[tok] * acc[i][r];
      }
    }
}

// ---------------- launch ----------------
extern "C" void kernel_launch(void* const* d_in, const int* in_sizes, int n_in,
                              void* d_out, int out_size, void* d_ws, size_t ws_size,
                              hipStream_t stream) {
  const float* x  = (const float*)d_in[0];
  const float* Wg = (const float*)d_in[1];
  const float* W1 = (const float*)d_in[2];
  const float* W2 = (const float*)d_in[3];
  const float* W3 = (const float*)d_in[4];
  float* out = (float*)d_out;
  char* ws = (char*)d_ws;

  int*            jbuf  = (int*)(ws + 0);
  float*          wbuf  = (float*)(ws + 8192);
  int*            cntp  = (int*)(ws + 16384);
  int*            basep = (int*)(ws + 16448);
  int*            list  = (int*)(ws + 16640);      // int[2048]
  int*            tl1   = (int*)(ws + 24832);      // int[40]
  int*            ntl   = (int*)(ws + 25600);      // int[2]
  unsigned short* xb    = (unsigned short*)(ws + 32768);                          // bf16 [2048][512]
  unsigned short* w1f   = (unsigned short*)(ws + 32768 + 2097152);                // frag [8][128][16][64][8]
  unsigned short* w3f   = (unsigned short*)(ws + 32768 + 2097152 + 16777216);
  unsigned short* w2f   = (unsigned short*)(ws + 32768 + 2097152 + 2 * 16777216); // frag [8][32][64][64][8]
  unsigned short* hbuf  = (unsigned short*)(ws + 32768 + 2097152 + 3 * 16777216); // bf16 [2048][2048]

  k_prep<<<dim3(6400), dim3(256), 0, stream>>>(x, Wg, W1, W3, W2, jbuf, wbuf, xb, w1f, w3f, w2f);
  k_bucket<<<dim3(1), dim3(256), 0, stream>>>(jbuf, cntp, basep, list, tl1, ntl);
  k_ffn1<<<dim3(640), dim3(256), 0, stream>>>(xb, w1f, w3f, cntp, basep, list, tl1, ntl, hbuf);
  k_ffn2<<<dim3(640), dim3(256), 0, stream>>>(hbuf, w2f, cntp, basep, list, tl1, ntl, wbuf, out);
}

// Round 12
// 82.872 us; speedup vs baseline: 1.4757x; 1.0006x over previous
//
#include <hip/hip_runtime.h>
#include <hip/hip_bf16.h>
#include <math.h>

typedef __attribute__((ext_vector_type(8))) short short8;
typedef __attribute__((ext_vector_type(4))) float f32x4;

#define T_TOK 2048
#define D_DIM 512
#define F_DIM 2048
#define E_NUM 8
#define MAXT1 40   // == sum_e ceil(cnt_e/64) upper bound (32 + 7 rounding)

__device__ __forceinline__ unsigned short f2bf(float f) {
  union { float f; unsigned u; } c; c.f = f;
  unsigned u = c.u;
  return (unsigned short)((u + 0x7fffu + ((u >> 16) & 1u)) >> 16);
}

__device__ __forceinline__ void gld16(const void* g, void* l) {
  __builtin_amdgcn_global_load_lds((const __attribute__((address_space(1))) int*)g,
                                   (__attribute__((address_space(3))) int*)l, 16, 0, 0);
}

// ---- prep mega-kernel: route (0..255) + wfrag1 (256..2303) + wfrag2 (2304..3327) ----
// wfrag: 64k x 128n tiles, 512B row bursts, rotation-swizzled LDS (stores b128
// conflict-free, transpose reads 2-way = free).
__global__ __launch_bounds__(256) void k_prep(const float* __restrict__ xin,
                                              const float* __restrict__ Wg,
                                              const float* __restrict__ W1,
                                              const float* __restrict__ W3,
                                              const float* __restrict__ W2,
                                              int* __restrict__ jbuf,
                                              float* __restrict__ wbuf,
                                              unsigned short* __restrict__ xb,
                                              unsigned short* __restrict__ w1f,
                                              unsigned short* __restrict__ w3f,
                                              unsigned short* __restrict__ w2f) {
  __shared__ float4 tile4[64 * 32];   // 32 KB
  int bz = blockIdx.x, tid = threadIdx.x;

  if (bz < 256) {
    // ---- routing: logits (32-way K-split) + top-2 + weight; converts x->bf16 ----
    int gid = bz * 256 + tid;
    int t = gid >> 5, seg = gid & 31;
    const float* xp = xin + (size_t)t * D_DIM + seg * 16;
    unsigned short* xo = xb + (size_t)t * D_DIM + seg * 16;
    float acc[8];
#pragma unroll
    for (int e = 0; e < 8; ++e) acc[e] = 0.f;
#pragma unroll
    for (int i = 0; i < 4; ++i) {
      float4 v = *(const float4*)(xp + i * 4);
      ushort4 o;
      o.x = f2bf(v.x); o.y = f2bf(v.y); o.z = f2bf(v.z); o.w = f2bf(v.w);
      *(ushort4*)(xo + i * 4) = o;
      const float* xs = (const float*)&v;
#pragma unroll
      for (int q = 0; q < 4; ++q) {
        int d = seg * 16 + i * 4 + q;
        const float4* wr = (const float4*)(Wg + (size_t)d * 8);
        float4 w0 = wr[0], w1 = wr[1];
        acc[0] += xs[q] * w0.x; acc[1] += xs[q] * w0.y;
        acc[2] += xs[q] * w0.z; acc[3] += xs[q] * w0.w;
        acc[4] += xs[q] * w1.x; acc[5] += xs[q] * w1.y;
        acc[6] += xs[q] * w1.z; acc[7] += xs[q] * w1.w;
      }
    }
#pragma unroll
    for (int off = 1; off < 32; off <<= 1)
#pragma unroll
      for (int e = 0; e < 8; ++e) acc[e] += __shfl_xor(acc[e], off);
    if (seg == 0) {
      float l0 = -1e30f, l1 = -1e30f; int i0 = 0, i1 = 0;
#pragma unroll
      for (int e = 0; e < 8; ++e) {
        float l = acc[e];
        if (l > l0) { l1 = l0; i1 = i0; l0 = l; i0 = e; }
        else if (l > l1) { l1 = l; i1 = e; }
      }
      int j; float w;
      if (i0 > i1) { j = i0; w = 1.f / (1.f + expf(l1 - l0)); }
      else         { j = i1; w = 1.f / (1.f + expf(l0 - l1)); }
      jbuf[t] = j; wbuf[t] = w;
    }
    return;
  }

  // ---- weight reformat: [K][N] f32 -> fragment-major bf16 [N/16][K/32][64][8] ----
  const float* in; unsigned short* out;
  int K, N, n0, k0;
  if (bz < 2304) {                 // wfrag1: W1/W3, K=512, N=2048; 8k x 16n tiles/z
    int idx = bz - 256;            // [0,2048)
    int z = idx >> 7, rem = idx & 127;
    K = 512; N = 2048;
    n0 = (rem & 15) * 128; k0 = (rem >> 4) * 64;
    size_t zsz = (size_t)(K / 32) * (N / 16) * 512;
    if (z < 8) { in = W1 + (size_t)z * K * N;       out = w1f + (size_t)z * zsz; }
    else       { in = W3 + (size_t)(z - 8) * K * N; out = w3f + (size_t)(z - 8) * zsz; }
  } else {                         // wfrag2: W2, K=2048, N=512; 32k x 4n tiles/z
    int idx = bz - 2304;           // [0,1024)
    int z = idx >> 7, rem = idx & 127;
    K = 2048; N = 512;
    n0 = (rem & 3) * 128; k0 = (rem >> 2) * 64;
    size_t zsz = (size_t)(K / 32) * (N / 16) * 512;
    in = W2 + (size_t)z * K * N; out = w2f + (size_t)z * zsz;
  }
  {
    int lr = tid >> 5, lc = tid & 31;
#pragma unroll
    for (int it = 0; it < 8; ++it) {
      int row = it * 8 + lr;
      float4 v = *(const float4*)(in + (size_t)(k0 + row) * N + n0 + lc * 4);
      tile4[row * 32 + ((lc + (row >> 3) * 4) & 31)] = v;   // rotation swizzle
    }
  }
  __syncthreads();
  const float* tf = (const float*)tile4;
  int wv = tid >> 6, l = tid & 63;
  int n4l = (l & 15) >> 2, nr = l & 3, kg = (l >> 4) * 8;
#pragma unroll
  for (int q = 0; q < 4; ++q) {
    int fid = wv * 4 + q;
    int nb = fid >> 1, kb = fid & 1;
    int n4 = nb * 4 + n4l;
    short8 o;
#pragma unroll
    for (int j = 0; j < 8; ++j) {
      int k = kb * 32 + kg + j;
      int slot = k * 32 + ((n4 + (k >> 3) * 4) & 31);
      o[j] = (short)f2bf(tf[slot * 4 + nr]);
    }
    unsigned short* op = out + (((size_t)(n0 / 16 + nb) * (K / 32)) + (k0 / 32 + kb)) * 512 + l * 8;
    *(short8*)op = o;
  }
}

// ---- bucket: counts, bases, compact token list, compact tile list (BM=64) ----
__global__ __launch_bounds__(256) void k_bucket(const int* __restrict__ jbuf,
                                                int* __restrict__ cntp,
                                                int* __restrict__ basep,
                                                int* __restrict__ list,
                                                int* __restrict__ tl1,
                                                int* __restrict__ ntl) {
  __shared__ int scnt[8], scur[8];
  int tid = threadIdx.x;
  if (tid < 8) scnt[tid] = 0;
  __syncthreads();
  for (int t = tid; t < T_TOK; t += 256) atomicAdd(&scnt[jbuf[t]], 1);
  __syncthreads();
  if (tid == 0) {
    int run = 0;
    for (int e = 0; e < 8; ++e) {
      cntp[e] = scnt[e]; basep[e] = run; scur[e] = run;
      run += scnt[e];
    }
    int n1 = 0, bb = 0;
    for (int e = 0; e < 8; ++e) {
      for (int m = 0; m < scnt[e]; m += 64) tl1[n1++] = (e << 16) | (bb + m);
      bb += scnt[e];
    }
    ntl[0] = n1;
  }
  __syncthreads();
  for (int t = tid; t < T_TOK; t += 256) {
    int j = jbuf[t];
    int p = atomicAdd(&scur[j], 1);
    list[p] = t;
  }
}

// ---- pass 1: A staged once; 4 panels with half-K register ping-pong B prefetch ----
__global__ __launch_bounds__(256, 2) void k_ffn1(const unsigned short* __restrict__ xb,
                                                 const unsigned short* __restrict__ w1f,
                                                 const unsigned short* __restrict__ w3f,
                                                 const int* __restrict__ cntp,
                                                 const int* __restrict__ basep,
                                                 const int* __restrict__ list,
                                                 const int* __restrict__ tl1,
                                                 const int* __restrict__ ntl,
                                                 unsigned short* __restrict__ hbuf) {
  int L = blockIdx.x;
  int b = (L & 7) * 80 + (L >> 3);     // XCD owns 2 col-groups x all m-tiles
  int x = b % 40, y = b / 40;          // x: m-tile, y: 128-col panel group
  if (x >= ntl[0]) return;
  int pk = tl1[x];
  int e = pk >> 16, g0 = pk & 0xffff;
  int lim = basep[e] + cntp[e];
  __shared__ unsigned short sA[64 * 512];   // 64 KB, XOR-swizzled 16B slots
  int tid = threadIdx.x, wv = tid >> 6, l = tid & 63;
  int wr = wv >> 1, wc = wv & 1;

  // one-time A stage: wave wv stages rows wv*16..+15
#pragma unroll
  for (int it = 0; it < 16; ++it) {
    int row = wv * 16 + it;
    int gr = g0 + row; if (gr >= lim) gr = lim - 1;
    int tok = list[gr];
    int slot = (l & 56) | ((l & 7) ^ (row & 7));
    gld16(xb + (size_t)tok * D_DIM + slot * 8, sA + row * 512);
  }

  const unsigned short* w1b = w1f + ((size_t)(e * 128 + y * 8 + wc) * 16) * 512 + l * 8;
  const unsigned short* w3b = w3f + ((size_t)(e * 128 + y * 8 + wc) * 16) * 512 + l * 8;

  short8 P1[8], P3[8], Q1[8], Q3[8];
  auto loadS = [&](short8* r1, short8* r3, int s) {   // s = panel*2 + half
    int g = s >> 1, h = s & 1;
    const unsigned short* p1 = w1b + ((size_t)(g * 32 + h * 8)) * 512;
    const unsigned short* p3 = w3b + ((size_t)(g * 32 + h * 8)) * 512;
#pragma unroll
    for (int q = 0; q < 8; ++q) {
      r1[q] = *(const short8*)(p1 + (size_t)q * 512);
      r3[q] = *(const short8*)(p3 + (size_t)q * 512);
    }
  };

  f32x4 au[2], av[2];
  auto halfC = [&](const short8* r1, const short8* r3, int h) {
#pragma unroll
    for (int q = 0; q < 8; ++q) {
      int kf = h * 8 + q;
      short8 a[2];
#pragma unroll
      for (int i = 0; i < 2; ++i) {
        int r = wr * 32 + i * 16 + (l & 15);
        int slot = kf * 4 + (l >> 4);
        int swz = (slot & 56) | ((slot & 7) ^ (r & 7));
        a[i] = *(const short8*)(sA + r * 512 + swz * 8);
      }
#pragma unroll
      for (int i = 0; i < 2; ++i) {
        au[i] = __builtin_amdgcn_mfma_f32_16x16x32_bf16(a[i], r1[q], au[i], 0, 0, 0);
        av[i] = __builtin_amdgcn_mfma_f32_16x16x32_bf16(a[i], r3[q], av[i], 0, 0, 0);
      }
    }
  };

  loadS(P1, P3, 0);
  __syncthreads();   // sA ready (the only barrier)

  int cloc = l & 15, rb = (l >> 4) * 4;
#pragma unroll
  for (int gp = 0; gp < 4; ++gp) {
#pragma unroll
    for (int i = 0; i < 2; ++i) {
      au[i] = (f32x4){0.f, 0.f, 0.f, 0.f};
      av[i] = (f32x4){0.f, 0.f, 0.f, 0.f};
    }
    loadS(Q1, Q3, gp * 2 + 1);        // prefetch 2nd half while computing 1st
    halfC(P1, P3, 0);
    if (gp < 3) loadS(P1, P3, gp * 2 + 2);   // prefetch next panel's 1st half
    halfC(Q1, Q3, 1);
    int col = (y * 4 + gp) * 32 + wc * 16 + cloc;
#pragma unroll
    for (int i = 0; i < 2; ++i)
#pragma unroll
      for (int r = 0; r < 4; ++r) {
        int gr = g0 + wr * 32 + i * 16 + rb + r;
        if (gr < lim) {
          float uu = au[i][r], vv = av[i][r];
          float hh = (uu / (1.f + expf(-uu))) * vv;
          hbuf[(size_t)gr * F_DIM + col] = f2bf(hh);
        }
      }
  }
}

// ---- pass 2: y = h @ W2; BM=64 BN=32 BK=128; XCD owns 5 m-tiles x all panels ----
__global__ __launch_bounds__(256, 3) void k_ffn2(const unsigned short* __restrict__ hbuf,
                                                 const unsigned short* __restrict__ w2f,
                                                 const int* __restrict__ cntp,
                                                 const int* __restrict__ basep,
                                                 const int* __restrict__ list,
                                                 const int* __restrict__ tl1,
                                                 const int* __restrict__ ntl,
                                                 const float* __restrict__ wbuf,
                                                 float* __restrict__ out) {
  int L = blockIdx.x;
  int c = L & 7, q = L >> 3;           // q in [0,80)
  int x = c * 5 + (q % 5);             // m-tile: XCD c owns [5c, 5c+5)
  int nt = q / 5;                      // 32-col d-panel [0,16)
  if (x >= ntl[0]) return;
  int pk = tl1[x];
  int e = pk >> 16, g0 = pk & 0xffff;
  int lim = basep[e] + cntp[e];
  __shared__ unsigned short sA[2 * 8192];   // 2 x 16 KB chunks [64][128], swizzled
  int tid = threadIdx.x, wv = tid >> 6, l = tid & 63;
  int wr = wv >> 1, wc = wv & 1;

  auto stage = [&](int buf, int ck) {
#pragma unroll
    for (int it = 0; it < 4; ++it) {
      int row0 = it * 16 + wv * 4;             // wave-uniform
      int row = row0 + (l >> 4);
      int gr = g0 + row; if (gr > T_TOK - 1) gr = T_TOK - 1;
      int sl = (l & 8) | ((l & 7) ^ (row & 7));
      gld16(hbuf + (size_t)gr * F_DIM + ck * 128 + sl * 8, sA + buf * 8192 + row0 * 128);
    }
  };

  // w2f frag (nb, kf) at (nb*64 + kf)*512; nb = nt*2 + wc
  const unsigned short* b2p = w2f + ((size_t)(e * 32 + nt * 2 + wc) * 64) * 512 + l * 8;

  short8 Ba[4], Bb[4];
  auto loadB = [&](short8* B, int ck) {
#pragma unroll
    for (int kk = 0; kk < 4; ++kk)
      B[kk] = *(const short8*)(b2p + (size_t)(ck * 4 + kk) * 512);
  };

  f32x4 acc[2];
  acc[0] = (f32x4){0.f, 0.f, 0.f, 0.f};
  acc[1] = (f32x4){0.f, 0.f, 0.f, 0.f};

  auto compute = [&](const short8* B, int cur) {
#pragma unroll
    for (int kk = 0; kk < 4; ++kk) {
      short8 a[2];
#pragma unroll
      for (int i = 0; i < 2; ++i) {
        int r = wr * 32 + i * 16 + (l & 15);
        int slot = kk * 4 + (l >> 4);
        int swz = (slot & 8) | ((slot & 7) ^ (r & 7));
        a[i] = *(const short8*)(sA + cur * 8192 + r * 128 + swz * 8);
      }
      acc[0] = __builtin_amdgcn_mfma_f32_16x16x32_bf16(a[0], B[kk], acc[0], 0, 0, 0);
      acc[1] = __builtin_amdgcn_mfma_f32_16x16x32_bf16(a[1], B[kk], acc[1], 0, 0, 0);
    }
  };

  stage(0, 0);
  loadB(Ba, 0);
  __syncthreads();
  int cur = 0;
  for (int ck = 0; ck < 16; ck += 2) {
    stage(cur ^ 1, ck + 1);
    loadB(Bb, ck + 1);
    compute(Ba, cur);
    __syncthreads();
    cur ^= 1;
    if (ck + 2 < 16) {
      stage(cur ^ 1, ck + 2);
      loadB(Ba, ck + 2);
    }
    compute(Bb, cur);
    __syncthreads();
    cur ^= 1;
  }

  int cloc = l & 15, rb = (l >> 4) * 4;
#pragma unroll
  for (int i = 0; i < 2; ++i)
#pragma unroll
    for (int r = 0; r < 4; ++r) {
      int gr = g0 + wr * 32 + i * 16 + rb + r;
      if (gr < lim) {
        int tok = list[gr];
        out[(size_t)tok * D_DIM + nt * 32 + wc * 16 + cloc] = wbuf[tok] * acc[i][r];
      }
    }
}

// ---------------- launch ----------------
extern "C" void kernel_launch(void* const* d_in, const int* in_sizes, int n_in,
                              void* d_out, int out_size, void* d_ws, size_t ws_size,
                              hipStream_t stream) {
  const float* x  = (const float*)d_in[0];
  const float* Wg = (const float*)d_in[1];
  const float* W1 = (const float*)d_in[2];
  const float* W2 = (const float*)d_in[3];
  const float* W3 = (const float*)d_in[4];
  float* out = (float*)d_out;
  char* ws = (char*)d_ws;

  int*            jbuf  = (int*)(ws + 0);
  float*          wbuf  = (float*)(ws + 8192);
  int*            cntp  = (int*)(ws + 16384);
  int*            basep = (int*)(ws + 16448);
  int*            list  = (int*)(ws + 16640);      // int[2048]
  int*            tl1   = (int*)(ws + 24832);      // int[40]
  int*            ntl   = (int*)(ws + 25600);      // int[2]
  unsigned short* xb    = (unsigned short*)(ws + 32768);                          // bf16 [2048][512]
  unsigned short* w1f   = (unsigned short*)(ws + 32768 + 2097152);                // frag [8][128][16][64][8]
  unsigned short* w3f   = (unsigned short*)(ws + 32768 + 2097152 + 16777216);
  unsigned short* w2f   = (unsigned short*)(ws + 32768 + 2097152 + 2 * 16777216); // frag [8][32][64][64][8]
  unsigned short* hbuf  = (unsigned short*)(ws + 32768 + 2097152 + 3 * 16777216); // bf16 [2048][2048]

  k_prep<<<dim3(3328), dim3(256), 0, stream>>>(x, Wg, W1, W3, W2, jbuf, wbuf, xb, w1f, w3f, w2f);
  k_bucket<<<dim3(1), dim3(256), 0, stream>>>(jbuf, cntp, basep, list, tl1, ntl);
  k_ffn1<<<dim3(640), dim3(256), 0, stream>>>(xb, w1f, w3f, cntp, basep, list, tl1, ntl, hbuf);
  k_ffn2<<<dim3(640), dim3(256), 0, stream>>>(hbuf, w2f, cntp, basep, list, tl1, ntl, wbuf, out);
}

// Round 13
// 79.821 us; speedup vs baseline: 1.5321x; 1.0382x over previous
//
#include <hip/hip_runtime.h>
#include <hip/hip_bf16.h>
#include <math.h>

typedef __attribute__((ext_vector_type(8))) short short8;
typedef __attribute__((ext_vector_type(4))) float f32x4;

#define T_TOK 2048
#define D_DIM 512
#define F_DIM 2048
#define E_NUM 8
#define MAXT1 40   // == sum_e ceil(cnt_e/64) upper bound (32 + 7 rounding)

__device__ __forceinline__ unsigned short f2bf(float f) {
  union { float f; unsigned u; } c; c.f = f;
  unsigned u = c.u;
  return (unsigned short)((u + 0x7fffu + ((u >> 16) & 1u)) >> 16);
}

__device__ __forceinline__ void gld16(const void* g, void* l) {
  __builtin_amdgcn_global_load_lds((const __attribute__((address_space(1))) int*)g,
                                   (__attribute__((address_space(3))) int*)l, 16, 0, 0);
}

// ---- prep: route (blocks 0..255) + wfrag1 W1/W3 (256..2303) ----
__global__ __launch_bounds__(256) void k_prep(const float* __restrict__ xin,
                                              const float* __restrict__ Wg,
                                              const float* __restrict__ W1,
                                              const float* __restrict__ W3,
                                              int* __restrict__ jbuf,
                                              float* __restrict__ wbuf,
                                              unsigned short* __restrict__ xb,
                                              unsigned short* __restrict__ w1f,
                                              unsigned short* __restrict__ w3f) {
  __shared__ float4 tile4[64 * 32];   // 32 KB
  int bz = blockIdx.x, tid = threadIdx.x;

  if (bz < 256) {
    // ---- routing: logits (32-way K-split) + top-2 + weight; converts x->bf16 ----
    int gid = bz * 256 + tid;
    int t = gid >> 5, seg = gid & 31;
    const float* xp = xin + (size_t)t * D_DIM + seg * 16;
    unsigned short* xo = xb + (size_t)t * D_DIM + seg * 16;
    float acc[8];
#pragma unroll
    for (int e = 0; e < 8; ++e) acc[e] = 0.f;
#pragma unroll
    for (int i = 0; i < 4; ++i) {
      float4 v = *(const float4*)(xp + i * 4);
      ushort4 o;
      o.x = f2bf(v.x); o.y = f2bf(v.y); o.z = f2bf(v.z); o.w = f2bf(v.w);
      *(ushort4*)(xo + i * 4) = o;
      const float* xs = (const float*)&v;
#pragma unroll
      for (int q = 0; q < 4; ++q) {
        int d = seg * 16 + i * 4 + q;
        const float4* wr = (const float4*)(Wg + (size_t)d * 8);
        float4 w0 = wr[0], w1 = wr[1];
        acc[0] += xs[q] * w0.x; acc[1] += xs[q] * w0.y;
        acc[2] += xs[q] * w0.z; acc[3] += xs[q] * w0.w;
        acc[4] += xs[q] * w1.x; acc[5] += xs[q] * w1.y;
        acc[6] += xs[q] * w1.z; acc[7] += xs[q] * w1.w;
      }
    }
#pragma unroll
    for (int off = 1; off < 32; off <<= 1)
#pragma unroll
      for (int e = 0; e < 8; ++e) acc[e] += __shfl_xor(acc[e], off);
    if (seg == 0) {
      float l0 = -1e30f, l1 = -1e30f; int i0 = 0, i1 = 0;
#pragma unroll
      for (int e = 0; e < 8; ++e) {
        float l = acc[e];
        if (l > l0) { l1 = l0; i1 = i0; l0 = l; i0 = e; }
        else if (l > l1) { l1 = l; i1 = e; }
      }
      int j; float w;
      if (i0 > i1) { j = i0; w = 1.f / (1.f + expf(l1 - l0)); }
      else         { j = i1; w = 1.f / (1.f + expf(l0 - l1)); }
      jbuf[t] = j; wbuf[t] = w;
    }
    return;
  }

  // ---- wfrag1: W1/W3 [512][2048] f32 -> frag bf16; 64k x 128n tiles ----
  int idx = bz - 256;            // [0,2048)
  int z = idx >> 7, rem = idx & 127;
  const int K = 512, N = 2048;
  int n0 = (rem & 15) * 128, k0 = (rem >> 4) * 64;
  size_t zsz = (size_t)(K / 32) * (N / 16) * 512;
  const float* in; unsigned short* out;
  if (z < 8) { in = W1 + (size_t)z * K * N;       out = w1f + (size_t)z * zsz; }
  else       { in = W3 + (size_t)(z - 8) * K * N; out = w3f + (size_t)(z - 8) * zsz; }
  {
    int lr = tid >> 5, lc = tid & 31;
#pragma unroll
    for (int it = 0; it < 8; ++it) {
      int row = it * 8 + lr;
      float4 v = *(const float4*)(in + (size_t)(k0 + row) * N + n0 + lc * 4);
      tile4[row * 32 + ((lc + (row >> 3) * 4) & 31)] = v;   // rotation swizzle
    }
  }
  __syncthreads();
  const float* tf = (const float*)tile4;
  int wv = tid >> 6, l = tid & 63;
  int n4l = (l & 15) >> 2, nr = l & 3, kg = (l >> 4) * 8;
#pragma unroll
  for (int q = 0; q < 4; ++q) {
    int fid = wv * 4 + q;
    int nb = fid >> 1, kb = fid & 1;
    int n4 = nb * 4 + n4l;
    short8 o;
#pragma unroll
    for (int j = 0; j < 8; ++j) {
      int k = kb * 32 + kg + j;
      int slot = k * 32 + ((n4 + (k >> 3) * 4) & 31);
      o[j] = (short)f2bf(tf[slot * 4 + nr]);
    }
    unsigned short* op = out + (((size_t)(n0 / 16 + nb) * (K / 32)) + (k0 / 32 + kb)) * 512 + l * 8;
    *(short8*)op = o;
  }
}

// ---- bucket: counts, bases, compact token list, compact tile list (BM=64) ----
__global__ __launch_bounds__(256) void k_bucket(const int* __restrict__ jbuf,
                                                int* __restrict__ cntp,
                                                int* __restrict__ basep,
                                                int* __restrict__ list,
                                                int* __restrict__ tl1,
                                                int* __restrict__ ntl) {
  __shared__ int scnt[8], scur[8];
  int tid = threadIdx.x;
  if (tid < 8) scnt[tid] = 0;
  __syncthreads();
  for (int t = tid; t < T_TOK; t += 256) atomicAdd(&scnt[jbuf[t]], 1);
  __syncthreads();
  if (tid == 0) {
    int run = 0;
    for (int e = 0; e < 8; ++e) {
      cntp[e] = scnt[e]; basep[e] = run; scur[e] = run;
      run += scnt[e];
    }
    int n1 = 0, bb = 0;
    for (int e = 0; e < 8; ++e) {
      for (int m = 0; m < scnt[e]; m += 64) tl1[n1++] = (e << 16) | (bb + m);
      bb += scnt[e];
    }
    ntl[0] = n1;
  }
  __syncthreads();
  for (int t = tid; t < T_TOK; t += 256) {
    int j = jbuf[t];
    int p = atomicAdd(&scur[j], 1);
    list[p] = t;
  }
}

// ---- fused: ffn1 (blocks 0..639, exact R12 structure) + wfrag2 (640..1663) ----
__global__ __launch_bounds__(256, 2) void k_ffn1w2(const unsigned short* __restrict__ xb,
                                                   const unsigned short* __restrict__ w1f,
                                                   const unsigned short* __restrict__ w3f,
                                                   const float* __restrict__ W2,
                                                   unsigned short* __restrict__ w2f,
                                                   const int* __restrict__ cntp,
                                                   const int* __restrict__ basep,
                                                   const int* __restrict__ list,
                                                   const int* __restrict__ tl1,
                                                   const int* __restrict__ ntl,
                                                   unsigned short* __restrict__ hbuf) {
  __shared__ unsigned short sA[64 * 512];   // 64 KB (ffn1: A tile; wfrag2: reuse as tile4)
  int tid = threadIdx.x, wv = tid >> 6, l = tid & 63;

  if (blockIdx.x >= 640) {
    // ---- wfrag2: W2 [2048][512] f32 -> frag bf16; 64k x 128n tiles ----
    int idx = blockIdx.x - 640;    // [0,1024)
    int z = idx >> 7, rem = idx & 127;
    const int K = 2048, N = 512;
    int n0 = (rem & 3) * 128, k0 = (rem >> 2) * 64;
    size_t zsz = (size_t)(K / 32) * (N / 16) * 512;
    const float* in = W2 + (size_t)z * K * N;
    unsigned short* out = w2f + (size_t)z * zsz;
    float4* tile4 = (float4*)sA;
    {
      int lr = tid >> 5, lc = tid & 31;
#pragma unroll
      for (int it = 0; it < 8; ++it) {
        int row = it * 8 + lr;
        float4 v = *(const float4*)(in + (size_t)(k0 + row) * N + n0 + lc * 4);
        tile4[row * 32 + ((lc + (row >> 3) * 4) & 31)] = v;   // rotation swizzle
      }
    }
    __syncthreads();
    const float* tf = (const float*)tile4;
    int n4l = (l & 15) >> 2, nr = l & 3, kg = (l >> 4) * 8;
#pragma unroll
    for (int q = 0; q < 4; ++q) {
      int fid = wv * 4 + q;
      int nb = fid >> 1, kb = fid & 1;
      int n4 = nb * 4 + n4l;
      short8 o;
#pragma unroll
      for (int j = 0; j < 8; ++j) {
        int k = kb * 32 + kg + j;
        int slot = k * 32 + ((n4 + (k >> 3) * 4) & 31);
        o[j] = (short)f2bf(tf[slot * 4 + nr]);
      }
      unsigned short* op = out + (((size_t)(n0 / 16 + nb) * (K / 32)) + (k0 / 32 + kb)) * 512 + l * 8;
      *(short8*)op = o;
    }
    return;
  }

  // ---- ffn1: A staged once; 4 panels, half-K register ping-pong B prefetch ----
  int L = blockIdx.x;
  int b = (L & 7) * 80 + (L >> 3);     // XCD owns 2 col-groups x all m-tiles
  int x = b % 40, y = b / 40;          // x: m-tile, y: 128-col panel group
  if (x >= ntl[0]) return;
  int pk = tl1[x];
  int e = pk >> 16, g0 = pk & 0xffff;
  int lim = basep[e] + cntp[e];
  int wr = wv >> 1, wc = wv & 1;

#pragma unroll
  for (int it = 0; it < 16; ++it) {
    int row = wv * 16 + it;
    int gr = g0 + row; if (gr >= lim) gr = lim - 1;
    int tok = list[gr];
    int slot = (l & 56) | ((l & 7) ^ (row & 7));
    gld16(xb + (size_t)tok * D_DIM + slot * 8, sA + row * 512);
  }

  const unsigned short* w1b = w1f + ((size_t)(e * 128 + y * 8 + wc) * 16) * 512 + l * 8;
  const unsigned short* w3b = w3f + ((size_t)(e * 128 + y * 8 + wc) * 16) * 512 + l * 8;

  short8 P1[8], P3[8], Q1[8], Q3[8];
  auto loadS = [&](short8* r1, short8* r3, int s) {   // s = panel*2 + half
    int g = s >> 1, h = s & 1;
    const unsigned short* p1 = w1b + ((size_t)(g * 32 + h * 8)) * 512;
    const unsigned short* p3 = w3b + ((size_t)(g * 32 + h * 8)) * 512;
#pragma unroll
    for (int q = 0; q < 8; ++q) {
      r1[q] = *(const short8*)(p1 + (size_t)q * 512);
      r3[q] = *(const short8*)(p3 + (size_t)q * 512);
    }
  };

  f32x4 au[2], av[2];
  auto halfC = [&](const short8* r1, const short8* r3, int h) {
#pragma unroll
    for (int q = 0; q < 8; ++q) {
      int kf = h * 8 + q;
      short8 a[2];
#pragma unroll
      for (int i = 0; i < 2; ++i) {
        int r = wr * 32 + i * 16 + (l & 15);
        int slot = kf * 4 + (l >> 4);
        int swz = (slot & 56) | ((slot & 7) ^ (r & 7));
        a[i] = *(const short8*)(sA + r * 512 + swz * 8);
      }
#pragma unroll
      for (int i = 0; i < 2; ++i) {
        au[i] = __builtin_amdgcn_mfma_f32_16x16x32_bf16(a[i], r1[q], au[i], 0, 0, 0);
        av[i] = __builtin_amdgcn_mfma_f32_16x16x32_bf16(a[i], r3[q], av[i], 0, 0, 0);
      }
    }
  };

  loadS(P1, P3, 0);
  __syncthreads();   // sA ready (the only barrier)

  int cloc = l & 15, rb = (l >> 4) * 4;
#pragma unroll
  for (int gp = 0; gp < 4; ++gp) {
#pragma unroll
    for (int i = 0; i < 2; ++i) {
      au[i] = (f32x4){0.f, 0.f, 0.f, 0.f};
      av[i] = (f32x4){0.f, 0.f, 0.f, 0.f};
    }
    loadS(Q1, Q3, gp * 2 + 1);        // prefetch 2nd half while computing 1st
    halfC(P1, P3, 0);
    if (gp < 3) loadS(P1, P3, gp * 2 + 2);   // prefetch next panel's 1st half
    halfC(Q1, Q3, 1);
    int col = (y * 4 + gp) * 32 + wc * 16 + cloc;
#pragma unroll
    for (int i = 0; i < 2; ++i)
#pragma unroll
      for (int r = 0; r < 4; ++r) {
        int gr = g0 + wr * 32 + i * 16 + rb + r;
        if (gr < lim) {
          float uu = au[i][r], vv = av[i][r];
          float hh = (uu / (1.f + expf(-uu))) * vv;
          hbuf[(size_t)gr * F_DIM + col] = f2bf(hh);
        }
      }
  }
}

// ---- pass 2: y = h @ W2; BM=64 BN=32 BK=128; XCD owns 5 m-tiles x all panels ----
__global__ __launch_bounds__(256, 3) void k_ffn2(const unsigned short* __restrict__ hbuf,
                                                 const unsigned short* __restrict__ w2f,
                                                 const int* __restrict__ cntp,
                                                 const int* __restrict__ basep,
                                                 const int* __restrict__ list,
                                                 const int* __restrict__ tl1,
                                                 const int* __restrict__ ntl,
                                                 const float* __restrict__ wbuf,
                                                 float* __restrict__ out) {
  int L = blockIdx.x;
  int c = L & 7, q = L >> 3;           // q in [0,80)
  int x = c * 5 + (q % 5);             // m-tile: XCD c owns [5c, 5c+5)
  int nt = q / 5;                      // 32-col d-panel [0,16)
  if (x >= ntl[0]) return;
  int pk = tl1[x];
  int e = pk >> 16, g0 = pk & 0xffff;
  int lim = basep[e] + cntp[e];
  __shared__ unsigned short sA[2 * 8192];   // 2 x 16 KB chunks [64][128], swizzled
  int tid = threadIdx.x, wv = tid >> 6, l = tid & 63;
  int wr = wv >> 1, wc = wv & 1;

  auto stage = [&](int buf, int ck) {
#pragma unroll
    for (int it = 0; it < 4; ++it) {
      int row0 = it * 16 + wv * 4;             // wave-uniform
      int row = row0 + (l >> 4);
      int gr = g0 + row; if (gr > T_TOK - 1) gr = T_TOK - 1;
      int sl = (l & 8) | ((l & 7) ^ (row & 7));
      gld16(hbuf + (size_t)gr * F_DIM + ck * 128 + sl * 8, sA + buf * 8192 + row0 * 128);
    }
  };

  // w2f frag (nb, kf) at (nb*64 + kf)*512; nb = nt*2 + wc
  const unsigned short* b2p = w2f + ((size_t)(e * 32 + nt * 2 + wc) * 64) * 512 + l * 8;

  short8 Ba[4], Bb[4];
  auto loadB = [&](short8* B, int ck) {
#pragma unroll
    for (int kk = 0; kk < 4; ++kk)
      B[kk] = *(const short8*)(b2p + (size_t)(ck * 4 + kk) * 512);
  };

  f32x4 acc[2];
  acc[0] = (f32x4){0.f, 0.f, 0.f, 0.f};
  acc[1] = (f32x4){0.f, 0.f, 0.f, 0.f};

  auto compute = [&](const short8* B, int cur) {
#pragma unroll
    for (int kk = 0; kk < 4; ++kk) {
      short8 a[2];
#pragma unroll
      for (int i = 0; i < 2; ++i) {
        int r = wr * 32 + i * 16 + (l & 15);
        int slot = kk * 4 + (l >> 4);
        int swz = (slot & 8) | ((slot & 7) ^ (r & 7));
        a[i] = *(const short8*)(sA + cur * 8192 + r * 128 + swz * 8);
      }
      acc[0] = __builtin_amdgcn_mfma_f32_16x16x32_bf16(a[0], B[kk], acc[0], 0, 0, 0);
      acc[1] = __builtin_amdgcn_mfma_f32_16x16x32_bf16(a[1], B[kk], acc[1], 0, 0, 0);
    }
  };

  stage(0, 0);
  loadB(Ba, 0);
  __syncthreads();
  int cur = 0;
  for (int ck = 0; ck < 16; ck += 2) {
    stage(cur ^ 1, ck + 1);
    loadB(Bb, ck + 1);
    compute(Ba, cur);
    __syncthreads();
    cur ^= 1;
    if (ck + 2 < 16) {
      stage(cur ^ 1, ck + 2);
      loadB(Ba, ck + 2);
    }
    compute(Bb, cur);
    __syncthreads();
    cur ^= 1;
  }

  int cloc = l & 15, rb = (l >> 4) * 4;
#pragma unroll
  for (int i = 0; i < 2; ++i)
#pragma unroll
    for (int r = 0; r < 4; ++r) {
      int gr = g0 + wr * 32 + i * 16 + rb + r;
      if (gr < lim) {
        int tok = list[gr];
        out[(size_t)tok * D_DIM + nt * 32 + wc * 16 + cloc] = wbuf[tok] * acc[i][r];
      }
    }
}

// ---------------- launch ----------------
extern "C" void kernel_launch(void* const* d_in, const int* in_sizes, int n_in,
                              void* d_out, int out_size, void* d_ws, size_t ws_size,
                              hipStream_t stream) {
  const float* x  = (const float*)d_in[0];
  const float* Wg = (const float*)d_in[1];
  const float* W1 = (const float*)d_in[2];
  const float* W2 = (const float*)d_in[3];
  const float* W3 = (const float*)d_in[4];
  float* out = (float*)d_out;
  char* ws = (char*)d_ws;

  int*            jbuf  = (int*)(ws + 0);
  float*          wbuf  = (float*)(ws + 8192);
  int*            cntp  = (int*)(ws + 16384);
  int*            basep = (int*)(ws + 16448);
  int*            list  = (int*)(ws + 16640);      // int[2048]
  int*            tl1   = (int*)(ws + 24832);      // int[40]
  int*            ntl   = (int*)(ws + 25600);      // int[2]
  unsigned short* xb    = (unsigned short*)(ws + 32768);                          // bf16 [2048][512]
  unsigned short* w1f   = (unsigned short*)(ws + 32768 + 2097152);                // frag [8][128][16][64][8]
  unsigned short* w3f   = (unsigned short*)(ws + 32768 + 2097152 + 16777216);
  unsigned short* w2f   = (unsigned short*)(ws + 32768 + 2097152 + 2 * 16777216); // frag [8][32][64][64][8]
  unsigned short* hbuf  = (unsigned short*)(ws + 32768 + 2097152 + 3 * 16777216); // bf16 [2048][2048]

  k_prep<<<dim3(2304), dim3(256), 0, stream>>>(x, Wg, W1, W3, jbuf, wbuf, xb, w1f, w3f);
  k_bucket<<<dim3(1), dim3(256), 0, stream>>>(jbuf, cntp, basep, list, tl1, ntl);
  k_ffn1w2<<<dim3(1664), dim3(256), 0, stream>>>(xb, w1f, w3f, W2, w2f, cntp, basep, list, tl1, ntl, hbuf);
  k_ffn2<<<dim3(640), dim3(256), 0, stream>>>(hbuf, w2f, cntp, basep, list, tl1, ntl, wbuf, out);
}